// Round 3
// baseline (810.473 us; speedup 1.0000x reference)
//
#include <hip/hip_runtime.h>
#include <hip/hip_bf16.h>

#define NN 16000
#define NE 128000

typedef unsigned short u16;

__device__ __forceinline__ float bf2f(u16 u) {
    unsigned int v = ((unsigned int)u) << 16;
    return __uint_as_float(v);
}
__device__ __forceinline__ u16 f2bf(float f) {
    unsigned int u = __float_as_uint(f);
    unsigned int r = u + 0x7FFF + ((u >> 16) & 1);
    return (u16)(r >> 16);
}
// flag-dispatched scalar load: bf=1 -> bf16 stream, bf=0 -> fp32 stream
__device__ __forceinline__ float loadf(const void* p, size_t i, int bf) {
    return bf ? bf2f(((const u16*)p)[i]) : ((const float*)p)[i];
}

// ---- dtype detect: is the float data bf16 (1) or fp32 (0)? -----------------
// bf16 N(0,1): u16 exponent bits (14:7) in [100,140] for ~100% of words.
// fp32 N(0,1) viewed as u16 stream: even words are mantissa halves (uniform
// exponent, ~16% in band), odd words in band -> ~58% total. Threshold 3300/4096.
__global__ void dtype_detect_kernel(const u16* __restrict__ xw, int* __restrict__ flags)
{
    __shared__ int cnt[256];
    int c = 0;
    for (int k = 0; k < 16; ++k) {
        unsigned int w = xw[threadIdx.x + k * 256];
        int e = (int)((w >> 7) & 0xFF);
        c += (e >= 100 && e <= 140) ? 1 : 0;
    }
    cnt[threadIdx.x] = c;
    __syncthreads();
    for (int s = 128; s > 0; s >>= 1) {
        if (threadIdx.x < s) cnt[threadIdx.x] += cnt[threadIdx.x + s];
        __syncthreads();
    }
    if (threadIdx.x == 0) flags[0] = (cnt[0] >= 3300) ? 1 : 0;
}

// ---- edge_index dtype detect (int64 vs int32): flags[1]=1 -> int64 ---------
__global__ void edetect_kernel(const int* __restrict__ ei, int* __restrict__ flags)
{
    __shared__ int acc[256];
    int a = 0;
    for (int i = threadIdx.x; i < NE; i += 256) a |= ei[2 * i + 1];
    acc[threadIdx.x] = a;
    __syncthreads();
    for (int s = 128; s > 0; s >>= 1) {
        if (threadIdx.x < s) acc[threadIdx.x] |= acc[threadIdx.x + s];
        __syncthreads();
    }
    if (threadIdx.x == 0) flags[1] = (acc[0] == 0) ? 1 : 0;
}

__global__ void cvt_edges_kernel(const int* __restrict__ ei, const int* __restrict__ flags,
                                 int* __restrict__ out)
{
    int i = blockIdx.x * 256 + threadIdx.x;
    if (i >= 2 * NE) return;
    int v = flags[1] ? ei[2 * i] : ei[i];
    v = v < 0 ? 0 : (v >= NN ? NN - 1 : v);  // clamp: never fault
    out[i] = v;
}

// ---------------- LayerNorm: (bf16|fp32) in -> fp32 out ---------------------
__global__ __launch_bounds__(256) void ln_in_kernel(const void* __restrict__ X,
                                                    const void* __restrict__ gain,
                                                    const void* __restrict__ beta,
                                                    const int* __restrict__ flags,
                                                    float* __restrict__ Y, int M)
{
    const int bf = flags[0];
    int row = blockIdx.x * 4 + (threadIdx.x >> 6);
    int lane = threadIdx.x & 63;
    if (row >= M) return;
    size_t base = (size_t)row * 128;
    float x0 = loadf(X, base + lane, bf);
    float x1 = loadf(X, base + lane + 64, bf);
    float s = x0 + x1, sq = x0 * x0 + x1 * x1;
    for (int m = 1; m < 64; m <<= 1) { s += __shfl_xor(s, m, 64); sq += __shfl_xor(sq, m, 64); }
    float mu = s * (1.0f / 128.0f);
    float var = sq * (1.0f / 128.0f) - mu * mu;
    float rs = rsqrtf(var + 1e-5f);
    Y[base + lane]      = (x0 - mu) * rs * loadf(gain, lane, bf)      + loadf(beta, lane, bf);
    Y[base + lane + 64] = (x1 - mu) * rs * loadf(gain, lane + 64, bf) + loadf(beta, lane + 64, bf);
}

// ---------------- LayerNorm: fp32 in -> fp32 out ----------------------------
__global__ __launch_bounds__(256) void ln_f32_kernel(const float* __restrict__ X,
                                                     const void* __restrict__ gain,
                                                     const void* __restrict__ beta,
                                                     const int* __restrict__ flags,
                                                     float* __restrict__ Y)
{
    const int bf = flags[0];
    int row = blockIdx.x * 4 + (threadIdx.x >> 6);
    int lane = threadIdx.x & 63;
    size_t base = (size_t)row * 128;
    float x0 = X[base + lane], x1 = X[base + lane + 64];
    float s = x0 + x1, sq = x0 * x0 + x1 * x1;
    for (int m = 1; m < 64; m <<= 1) { s += __shfl_xor(s, m, 64); sq += __shfl_xor(sq, m, 64); }
    float mu = s * (1.0f / 128.0f);
    float var = sq * (1.0f / 128.0f) - mu * mu;
    float rs = rsqrtf(var + 1e-5f);
    Y[base + lane]      = (x0 - mu) * rs * loadf(gain, lane, bf)      + loadf(beta, lane, bf);
    Y[base + lane + 64] = (x1 - mu) * rs * loadf(gain, lane + 64, bf) + loadf(beta, lane + 64, bf);
}

// ---------------- Generic tiled SGEMM: C = act(A @ W + bias) ----------------
// A fp32 [M,K], W (bf16|fp32) [K,Ncol], bias (bf16|fp32)[Ncol] or null,
// C fp32 [M,Ncol]. act: 0 none, 1 phi(elu+1), 2 gelu(exact).
__global__ __launch_bounds__(256) void gemm_kernel(const float* __restrict__ A,
                                                   const void* __restrict__ W,
                                                   const void* __restrict__ bias,
                                                   const int* __restrict__ flags,
                                                   float* __restrict__ C,
                                                   int M, int K, int Ncol, int act)
{
    const int bf = flags[0];
    __shared__ float As[64][17];
    __shared__ float Bs[16][64];
    int tid = threadIdx.x;
    int tx = tid & 15, ty = tid >> 4;
    int row0 = blockIdx.y * 64, col0 = blockIdx.x * 64;
    float acc[4][4] = {};
    int ar = tid >> 2, ac = (tid & 3) << 2;
    int wr = tid >> 4, wc = (tid & 15) << 2;
    for (int k0 = 0; k0 < K; k0 += 16) {
        float4 av = *(const float4*)(A + (size_t)(row0 + ar) * K + k0 + ac);
        As[ar][ac] = av.x; As[ar][ac + 1] = av.y; As[ar][ac + 2] = av.z; As[ar][ac + 3] = av.w;
        size_t woff = (size_t)(k0 + wr) * Ncol + col0 + wc;
        if (bf) {
            ushort4 wv = *(const ushort4*)((const u16*)W + woff);
            Bs[wr][wc] = bf2f(wv.x); Bs[wr][wc + 1] = bf2f(wv.y);
            Bs[wr][wc + 2] = bf2f(wv.z); Bs[wr][wc + 3] = bf2f(wv.w);
        } else {
            float4 wv = *(const float4*)((const float*)W + woff);
            Bs[wr][wc] = wv.x; Bs[wr][wc + 1] = wv.y;
            Bs[wr][wc + 2] = wv.z; Bs[wr][wc + 3] = wv.w;
        }
        __syncthreads();
        #pragma unroll
        for (int kk = 0; kk < 16; ++kk) {
            float a[4], b[4];
            #pragma unroll
            for (int i = 0; i < 4; i++) a[i] = As[ty * 4 + i][kk];
            #pragma unroll
            for (int j = 0; j < 4; j++) b[j] = Bs[kk][tx * 4 + j];
            #pragma unroll
            for (int i = 0; i < 4; i++)
                #pragma unroll
                for (int j = 0; j < 4; j++)
                    acc[i][j] = fmaf(a[i], b[j], acc[i][j]);
        }
        __syncthreads();
    }
    #pragma unroll
    for (int i = 0; i < 4; i++) {
        int r = row0 + ty * 4 + i;
        float* cp = C + (size_t)r * Ncol + col0 + tx * 4;
        #pragma unroll
        for (int j = 0; j < 4; j++) {
            float v = acc[i][j];
            int c = col0 + tx * 4 + j;
            if (bias) v += loadf(bias, c, bf);
            if (act == 1) v = (v > 0.0f) ? v + 1.0f : expf(v);
            else if (act == 2) v = 0.5f * v * (1.0f + erff(v * 0.70710678118f));
            cp[j] = v;
        }
    }
}

// -------- Fused edge pipeline: LN(r) -> +k[src]/v[src], phi, scatter --------
__global__ __launch_bounds__(256) void edge_fused_kernel(
    const void* __restrict__ r,
    const void* __restrict__ lng, const void* __restrict__ lnb,
    const void* __restrict__ Wkr, const void* __restrict__ Wvr,
    const int* __restrict__ flags,
    const int* __restrict__ src, const int* __restrict__ dst,
    const float* __restrict__ kb, const float* __restrict__ vb,
    const float* __restrict__ phiq,
    float* __restrict__ num, float* __restrict__ den)
{
    const int bf = flags[0];
    __shared__ float As[64][129];
    __shared__ float Ks[64][129];
    __shared__ float Bs[16][64];
    __shared__ float Ps[64][8];
    int tid = threadIdx.x;
    int e0 = blockIdx.x * 64;
    int tx = tid & 15, ty = tid >> 4;

    // --- load r rows + LayerNorm (4 threads per row) ---
    {
        int lr = tid >> 2, lc = (tid & 3) << 5;
        float vbuf[32];
        float s = 0.f, sq = 0.f;
        size_t roff = (size_t)(e0 + lr) * 128 + lc;
        if (bf) {
            const u16* rp = (const u16*)r + roff;
            #pragma unroll
            for (int j = 0; j < 32; j += 4) {
                ushort4 v4 = *(const ushort4*)(rp + j);
                float a = bf2f(v4.x), b = bf2f(v4.y), c = bf2f(v4.z), d = bf2f(v4.w);
                vbuf[j] = a; vbuf[j + 1] = b; vbuf[j + 2] = c; vbuf[j + 3] = d;
                s += a + b + c + d; sq += a * a + b * b + c * c + d * d;
            }
        } else {
            const float* rp = (const float*)r + roff;
            #pragma unroll
            for (int j = 0; j < 32; j += 4) {
                float4 v4 = *(const float4*)(rp + j);
                vbuf[j] = v4.x; vbuf[j + 1] = v4.y; vbuf[j + 2] = v4.z; vbuf[j + 3] = v4.w;
                s += v4.x + v4.y + v4.z + v4.w;
                sq += v4.x * v4.x + v4.y * v4.y + v4.z * v4.z + v4.w * v4.w;
            }
        }
        s += __shfl_xor(s, 1, 64); sq += __shfl_xor(sq, 1, 64);
        s += __shfl_xor(s, 2, 64); sq += __shfl_xor(sq, 2, 64);
        float mu = s * (1.0f / 128.0f);
        float var = sq * (1.0f / 128.0f) - mu * mu;
        float rs = rsqrtf(var + 1e-5f);
        #pragma unroll
        for (int j = 0; j < 32; ++j)
            As[lr][lc + j] = (vbuf[j] - mu) * rs * loadf(lng, lc + j, bf) + loadf(lnb, lc + j, bf);
    }
    __syncthreads();

    int se[4], de[4];
    #pragma unroll
    for (int i = 0; i < 4; i++) { se[i] = src[e0 + ty * 4 + i]; de[i] = dst[e0 + ty * 4 + i]; }

    // --- ke = As @ Wkr (+k[src], phi) -> Ks ---
    for (int cb = 0; cb < 2; ++cb) {
        float acc[4][4] = {};
        for (int k0 = 0; k0 < 128; k0 += 16) {
            int wr = tid >> 4, wc = (tid & 15) << 2;
            size_t woff = (size_t)(k0 + wr) * 128 + cb * 64 + wc;
            if (bf) {
                ushort4 w4 = *(const ushort4*)((const u16*)Wkr + woff);
                Bs[wr][wc] = bf2f(w4.x); Bs[wr][wc + 1] = bf2f(w4.y);
                Bs[wr][wc + 2] = bf2f(w4.z); Bs[wr][wc + 3] = bf2f(w4.w);
            } else {
                float4 w4 = *(const float4*)((const float*)Wkr + woff);
                Bs[wr][wc] = w4.x; Bs[wr][wc + 1] = w4.y;
                Bs[wr][wc + 2] = w4.z; Bs[wr][wc + 3] = w4.w;
            }
            __syncthreads();
            #pragma unroll
            for (int kk = 0; kk < 16; ++kk) {
                float a[4], b[4];
                #pragma unroll
                for (int i = 0; i < 4; i++) a[i] = As[ty * 4 + i][k0 + kk];
                #pragma unroll
                for (int j = 0; j < 4; j++) b[j] = Bs[kk][tx * 4 + j];
                #pragma unroll
                for (int i = 0; i < 4; i++)
                    #pragma unroll
                    for (int j = 0; j < 4; j++)
                        acc[i][j] = fmaf(a[i], b[j], acc[i][j]);
            }
            __syncthreads();
        }
        #pragma unroll
        for (int i = 0; i < 4; i++)
            #pragma unroll
            for (int j = 0; j < 4; j++) {
                int col = cb * 64 + tx * 4 + j;
                float kv = acc[i][j] + kb[(size_t)se[i] * 128 + col];
                Ks[ty * 4 + i][col] = (kv > 0.0f) ? kv + 1.0f : expf(kv);
            }
    }
    __syncthreads();

    // --- p[e][h] = <phiq[dst], Ks>, den scatter ---
    #pragma unroll
    for (int it = 0; it < 2; ++it) {
        int idx = it * 256 + tid;           // 0..511
        int e = idx >> 3, h = idx & 7;
        int dn = dst[e0 + e];
        const float* pq = phiq + (size_t)dn * 128 + h * 16;
        float p = 0.f;
        #pragma unroll
        for (int d2 = 0; d2 < 16; ++d2) p += pq[d2] * Ks[e][h * 16 + d2];
        Ps[e][h] = p;
        atomicAdd(&den[dn * 8 + h], p);
    }
    __syncthreads();

    // --- ve = As @ Wvr (+v[src]); num[dst] += p * ve ---
    for (int cb = 0; cb < 2; ++cb) {
        float acc[4][4] = {};
        for (int k0 = 0; k0 < 128; k0 += 16) {
            int wr = tid >> 4, wc = (tid & 15) << 2;
            size_t woff = (size_t)(k0 + wr) * 128 + cb * 64 + wc;
            if (bf) {
                ushort4 w4 = *(const ushort4*)((const u16*)Wvr + woff);
                Bs[wr][wc] = bf2f(w4.x); Bs[wr][wc + 1] = bf2f(w4.y);
                Bs[wr][wc + 2] = bf2f(w4.z); Bs[wr][wc + 3] = bf2f(w4.w);
            } else {
                float4 w4 = *(const float4*)((const float*)Wvr + woff);
                Bs[wr][wc] = w4.x; Bs[wr][wc + 1] = w4.y;
                Bs[wr][wc + 2] = w4.z; Bs[wr][wc + 3] = w4.w;
            }
            __syncthreads();
            #pragma unroll
            for (int kk = 0; kk < 16; ++kk) {
                float a[4], b[4];
                #pragma unroll
                for (int i = 0; i < 4; i++) a[i] = As[ty * 4 + i][k0 + kk];
                #pragma unroll
                for (int j = 0; j < 4; j++) b[j] = Bs[kk][tx * 4 + j];
                #pragma unroll
                for (int i = 0; i < 4; i++)
                    #pragma unroll
                    for (int j = 0; j < 4; j++)
                        acc[i][j] = fmaf(a[i], b[j], acc[i][j]);
            }
            __syncthreads();
        }
        #pragma unroll
        for (int i = 0; i < 4; i++)
            #pragma unroll
            for (int j = 0; j < 4; j++) {
                int col = cb * 64 + tx * 4 + j;
                float vv = acc[i][j] + vb[(size_t)se[i] * 128 + col];
                atomicAdd(&num[(size_t)de[i] * 128 + col], Ps[ty * 4 + i][col >> 4] * vv);
            }
    }
}

// ---------------- Normalize: att = num / max(den, 1e-6) ---------------------
__global__ void normalize_kernel(float* __restrict__ num, const float* __restrict__ den)
{
    int idx = blockIdx.x * 256 + threadIdx.x; // N*128
    int n = idx >> 7, h = (idx >> 4) & 7;
    float dd = fmaxf(den[n * 8 + h], 1e-6f);
    num[idx] = num[idx] / dd;
}

// ---------------- Concat [out | xs] -> cc [N,256] ---------------------------
__global__ void concat_kernel(const float* __restrict__ outp, const float* __restrict__ xs,
                              float* __restrict__ cc)
{
    int idx = blockIdx.x * 256 + threadIdx.x; // N*256
    int n = idx >> 8, j = idx & 255;
    cc[idx] = (j < 128) ? outp[(size_t)n * 128 + j] : xs[(size_t)n * 128 + (j - 128)];
}

// ------- Gate + post-LN + residual: xmid = x + LN(out + sig(g)*(s-out)) -----
__global__ __launch_bounds__(256) void gate_post_kernel(const float* __restrict__ outp,
                                                        const float* __restrict__ gpre,
                                                        const float* __restrict__ sbuf,
                                                        const void* __restrict__ x,
                                                        const void* __restrict__ gain,
                                                        const void* __restrict__ beta,
                                                        const int* __restrict__ flags,
                                                        float* __restrict__ xmid)
{
    const int bf = flags[0];
    int row = blockIdx.x * 4 + (threadIdx.x >> 6);
    int lane = threadIdx.x & 63;
    size_t base = (size_t)row * 128;
    float o0 = outp[base + lane], o1 = outp[base + lane + 64];
    float sg0 = 1.0f / (1.0f + expf(-gpre[base + lane]));
    float sg1 = 1.0f / (1.0f + expf(-gpre[base + lane + 64]));
    float a0 = o0 + sg0 * (sbuf[base + lane] - o0);
    float a1 = o1 + sg1 * (sbuf[base + lane + 64] - o1);
    float s = a0 + a1, sq = a0 * a0 + a1 * a1;
    for (int m = 1; m < 64; m <<= 1) { s += __shfl_xor(s, m, 64); sq += __shfl_xor(sq, m, 64); }
    float mu = s * (1.0f / 128.0f);
    float var = sq * (1.0f / 128.0f) - mu * mu;
    float rs = rsqrtf(var + 1e-5f);
    xmid[base + lane]      = loadf(x, base + lane, bf)      + (a0 - mu) * rs * loadf(gain, lane, bf)      + loadf(beta, lane, bf);
    xmid[base + lane + 64] = loadf(x, base + lane + 64, bf) + (a1 - mu) * rs * loadf(gain, lane + 64, bf) + loadf(beta, lane + 64, bf);
}

// ---------------- Final: out = (bf16|fp32)(xmid + LN(h2)) -------------------
__global__ __launch_bounds__(256) void final_kernel(const float* __restrict__ h2,
                                                    const float* __restrict__ xmid,
                                                    const void* __restrict__ gain,
                                                    const void* __restrict__ beta,
                                                    const int* __restrict__ flags,
                                                    void* __restrict__ outp)
{
    const int bf = flags[0];
    int row = blockIdx.x * 4 + (threadIdx.x >> 6);
    int lane = threadIdx.x & 63;
    size_t base = (size_t)row * 128;
    float x0 = h2[base + lane], x1 = h2[base + lane + 64];
    float s = x0 + x1, sq = x0 * x0 + x1 * x1;
    for (int m = 1; m < 64; m <<= 1) { s += __shfl_xor(s, m, 64); sq += __shfl_xor(sq, m, 64); }
    float mu = s * (1.0f / 128.0f);
    float var = sq * (1.0f / 128.0f) - mu * mu;
    float rs = rsqrtf(var + 1e-5f);
    float y0 = xmid[base + lane]      + (x0 - mu) * rs * loadf(gain, lane, bf)      + loadf(beta, lane, bf);
    float y1 = xmid[base + lane + 64] + (x1 - mu) * rs * loadf(gain, lane + 64, bf) + loadf(beta, lane + 64, bf);
    if (bf) {
        ((u16*)outp)[base + lane]      = f2bf(y0);
        ((u16*)outp)[base + lane + 64] = f2bf(y1);
    } else {
        ((float*)outp)[base + lane]      = y0;
        ((float*)outp)[base + lane + 64] = y1;
    }
}

// ---------------- Zero fill -------------------------------------------------
__global__ void zero_kernel(float* __restrict__ p, size_t n)
{
    size_t i = (size_t)blockIdx.x * 256 + threadIdx.x;
    if (i < n) p[i] = 0.0f;
}

extern "C" void kernel_launch(void* const* d_in, const int* in_sizes, int n_in,
                              void* d_out, int out_size, void* d_ws, size_t ws_size,
                              hipStream_t stream)
{
    const int N = NN, E = NE;
    const void* x       = d_in[0];
    const void* r       = d_in[1];
    const int*  ei      = (const int*)d_in[2];
    const void* ln_x_g  = d_in[3];
    const void* ln_x_b  = d_in[4];
    const void* ln_r_g  = d_in[5];
    const void* ln_r_b  = d_in[6];
    const void* ln_po_g = d_in[7];
    const void* ln_po_b = d_in[8];
    const void* ln_fp_g = d_in[9];
    const void* ln_fp_b = d_in[10];
    const void* ln_fo_g = d_in[11];
    const void* ln_fo_b = d_in[12];
    const void* Wq      = d_in[13];
    const void* Wk      = d_in[14];
    const void* Wv      = d_in[15];
    const void* Wkr     = d_in[16];
    const void* Wvr     = d_in[17];
    const void* Wo      = d_in[18];
    const void* Wg      = d_in[19];
    const void* bg      = d_in[20];
    const void* Ws      = d_in[21];
    const void* bs      = d_in[22];
    const void* W1      = d_in[23];
    const void* b1      = d_in[24];
    const void* W2      = d_in[25];
    const void* b2      = d_in[26];

    // ---- workspace (fp32), ~92 MB total ----
    float* ws = (float*)d_ws;
    size_t off = 0;
    auto alloc = [&](size_t n) { float* p = ws + off; off += n; return p; };
    float* xs   = alloc((size_t)N * 128);
    float* phiq = alloc((size_t)N * 128);
    float* kb   = alloc((size_t)N * 128);
    float* vb   = alloc((size_t)N * 128);
    float* num  = alloc((size_t)N * 128);
    float* den  = alloc((size_t)N * 8);      // contiguous after num
    float* outp = alloc((size_t)N * 128);
    float* sbuf = alloc((size_t)N * 128);
    float* gpre = alloc((size_t)N * 128);
    float* xmid = alloc((size_t)N * 128);
    float* ffp  = alloc((size_t)N * 128);
    float* h2   = alloc((size_t)N * 128);
    int*   e32  = (int*)alloc((size_t)2 * E);
    int*   flags= (int*)alloc(16);
    // overlays (time-disjoint): cc over phiq+kb, h1 over xs..vb
    float* cc = phiq;                 // N*256
    float* h1 = xs;                   // N*512

    const int* src = e32;
    const int* dst = e32 + E;

    // 0. dtype + edge-index detection, conversion
    dtype_detect_kernel<<<1, 256, 0, stream>>>((const u16*)x, flags);
    edetect_kernel<<<1, 256, 0, stream>>>(ei, flags);
    cvt_edges_kernel<<<(2 * E + 255) / 256, 256, 0, stream>>>(ei, flags, e32);

    // 1. pre-norm x
    ln_in_kernel<<<N / 4, 256, 0, stream>>>(x, ln_x_g, ln_x_b, flags, xs, N);

    // 2. node projections (phi fused into q)
    gemm_kernel<<<dim3(2, N / 64), 256, 0, stream>>>(xs, Wq, nullptr, flags, phiq, N, 128, 128, 1);
    gemm_kernel<<<dim3(2, N / 64), 256, 0, stream>>>(xs, Wk, nullptr, flags, kb,   N, 128, 128, 0);
    gemm_kernel<<<dim3(2, N / 64), 256, 0, stream>>>(xs, Wv, nullptr, flags, vb,   N, 128, 128, 0);

    // 3. zero accumulators (num+den contiguous)
    {
        size_t nz = (size_t)N * 128 + (size_t)N * 8;
        zero_kernel<<<(unsigned)((nz + 255) / 256), 256, 0, stream>>>(num, nz);
    }

    // 4. fused edge pipeline (LN(r), both edge GEMMs, phi, dot, scatter)
    edge_fused_kernel<<<E / 64, 256, 0, stream>>>(r, ln_r_g, ln_r_b, Wkr, Wvr, flags,
                                                  src, dst, kb, vb, phiq, num, den);

    // 5. normalize
    normalize_kernel<<<(N * 128) / 256, 256, 0, stream>>>(num, den);

    // 6. output projection + gate
    gemm_kernel<<<dim3(2, N / 64), 256, 0, stream>>>(num, Wo, nullptr, flags, outp, N, 128, 128, 0);
    gemm_kernel<<<dim3(2, N / 64), 256, 0, stream>>>(xs, Ws, bs, flags, sbuf, N, 128, 128, 0);
    concat_kernel<<<(N * 256) / 256, 256, 0, stream>>>(outp, xs, cc);
    gemm_kernel<<<dim3(2, N / 64), 256, 0, stream>>>(cc, Wg, bg, flags, gpre, N, 256, 128, 0);
    gate_post_kernel<<<N / 4, 256, 0, stream>>>(outp, gpre, sbuf, x, ln_po_g, ln_po_b, flags, xmid);

    // 7. feed-forward
    ln_f32_kernel<<<N / 4, 256, 0, stream>>>(xmid, ln_fp_g, ln_fp_b, flags, ffp);
    gemm_kernel<<<dim3(8, N / 64), 256, 0, stream>>>(ffp, W1, b1, flags, h1, N, 128, 512, 2);
    gemm_kernel<<<dim3(2, N / 64), 256, 0, stream>>>(h1, W2, b2, flags, h2, N, 512, 128, 0);

    // 8. final residual + LN -> out
    final_kernel<<<N / 4, 256, 0, stream>>>(h2, xmid, ln_fo_g, ln_fo_b, flags, d_out);
}

// Round 4
// 541.045 us; speedup vs baseline: 1.4980x; 1.4980x over previous
//
#include <hip/hip_runtime.h>
#include <hip/hip_bf16.h>

#define NN 16000
#define NE 128000

typedef unsigned short u16;
typedef __attribute__((ext_vector_type(8))) short bf16x8;
typedef __attribute__((ext_vector_type(4))) float f32x4;

__device__ __forceinline__ float bf2f(u16 u) {
    unsigned int v = ((unsigned int)u) << 16;
    return __uint_as_float(v);
}
__device__ __forceinline__ u16 f2bf(float f) {
    unsigned int u = __float_as_uint(f);
    unsigned int r = u + 0x7FFF + ((u >> 16) & 1);
    return (u16)(r >> 16);
}
// flag-dispatched scalar load: bf=1 -> bf16 stream, bf=0 -> fp32 stream
__device__ __forceinline__ float loadf(const void* p, size_t i, int bf) {
    return bf ? bf2f(((const u16*)p)[i]) : ((const float*)p)[i];
}

// ---- dtype detect: is the float data bf16 (1) or fp32 (0)? -----------------
__global__ void dtype_detect_kernel(const u16* __restrict__ xw, int* __restrict__ flags)
{
    __shared__ int cnt[256];
    int c = 0;
    for (int k = 0; k < 16; ++k) {
        unsigned int w = xw[threadIdx.x + k * 256];
        int e = (int)((w >> 7) & 0xFF);
        c += (e >= 100 && e <= 140) ? 1 : 0;
    }
    cnt[threadIdx.x] = c;
    __syncthreads();
    for (int s = 128; s > 0; s >>= 1) {
        if (threadIdx.x < s) cnt[threadIdx.x] += cnt[threadIdx.x + s];
        __syncthreads();
    }
    if (threadIdx.x == 0) flags[0] = (cnt[0] >= 3300) ? 1 : 0;
}

// ---- edge_index dtype detect (int64 vs int32): flags[1]=1 -> int64 ---------
__global__ void edetect_kernel(const int* __restrict__ ei, int* __restrict__ flags)
{
    __shared__ int acc[256];
    int a = 0;
    for (int i = threadIdx.x; i < NE; i += 256) a |= ei[2 * i + 1];
    acc[threadIdx.x] = a;
    __syncthreads();
    for (int s = 128; s > 0; s >>= 1) {
        if (threadIdx.x < s) acc[threadIdx.x] |= acc[threadIdx.x + s];
        __syncthreads();
    }
    if (threadIdx.x == 0) flags[1] = (acc[0] == 0) ? 1 : 0;
}

__global__ void cvt_edges_kernel(const int* __restrict__ ei, const int* __restrict__ flags,
                                 int* __restrict__ out)
{
    int i = blockIdx.x * 256 + threadIdx.x;
    if (i >= 2 * NE) return;
    int v = flags[1] ? ei[2 * i] : ei[i];
    v = v < 0 ? 0 : (v >= NN ? NN - 1 : v);
    out[i] = v;
}

// ---- weight transpose-convert: W[K][N] (bf16|fp32) -> Wt[N][K] bf16 --------
struct WDesc { const void* w; u16* wt; int K; int N; int tile0; };
struct WTArgs { WDesc d[10]; };
__global__ __launch_bounds__(256) void wtrans_kernel(WTArgs args, const int* __restrict__ flags)
{
    int b = blockIdx.x;
    int i = 0;
    while (i < 9 && b >= args.d[i + 1].tile0) ++i;
    WDesc de = args.d[i];
    int lt = b - de.tile0;
    int tn = de.N >> 5;
    int tk = lt / tn, tc = lt % tn;
    int bf = flags[0];
    int n = tc * 32 + (threadIdx.x & 31);
    int k = tk * 32 + ((threadIdx.x >> 5) << 2);
    u16* dp = de.wt + (size_t)n * de.K + k;
    #pragma unroll
    for (int j = 0; j < 4; ++j)
        dp[j] = f2bf(loadf(de.w, (size_t)(k + j) * de.N + n, bf));
}

// ---------------- LayerNorm: (bf16|fp32) in -> bf16 out ---------------------
__global__ __launch_bounds__(256) void ln_in_kernel(const void* __restrict__ X,
                                                    const void* __restrict__ gain,
                                                    const void* __restrict__ beta,
                                                    const int* __restrict__ flags,
                                                    u16* __restrict__ Y, int M)
{
    const int bf = flags[0];
    int row = blockIdx.x * 4 + (threadIdx.x >> 6);
    int lane = threadIdx.x & 63;
    if (row >= M) return;
    size_t base = (size_t)row * 128;
    float x0 = loadf(X, base + lane, bf);
    float x1 = loadf(X, base + lane + 64, bf);
    float s = x0 + x1, sq = x0 * x0 + x1 * x1;
    for (int m = 1; m < 64; m <<= 1) { s += __shfl_xor(s, m, 64); sq += __shfl_xor(sq, m, 64); }
    float mu = s * (1.0f / 128.0f);
    float var = sq * (1.0f / 128.0f) - mu * mu;
    float rs = rsqrtf(var + 1e-5f);
    Y[base + lane]      = f2bf((x0 - mu) * rs * loadf(gain, lane, bf)      + loadf(beta, lane, bf));
    Y[base + lane + 64] = f2bf((x1 - mu) * rs * loadf(gain, lane + 64, bf) + loadf(beta, lane + 64, bf));
}

// ---------------- LayerNorm: fp32 in -> bf16 out ----------------------------
__global__ __launch_bounds__(256) void ln_mid_kernel(const float* __restrict__ X,
                                                     const void* __restrict__ gain,
                                                     const void* __restrict__ beta,
                                                     const int* __restrict__ flags,
                                                     u16* __restrict__ Y)
{
    const int bf = flags[0];
    int row = blockIdx.x * 4 + (threadIdx.x >> 6);
    int lane = threadIdx.x & 63;
    size_t base = (size_t)row * 128;
    float x0 = X[base + lane], x1 = X[base + lane + 64];
    float s = x0 + x1, sq = x0 * x0 + x1 * x1;
    for (int m = 1; m < 64; m <<= 1) { s += __shfl_xor(s, m, 64); sq += __shfl_xor(sq, m, 64); }
    float mu = s * (1.0f / 128.0f);
    float var = sq * (1.0f / 128.0f) - mu * mu;
    float rs = rsqrtf(var + 1e-5f);
    Y[base + lane]      = f2bf((x0 - mu) * rs * loadf(gain, lane, bf)      + loadf(beta, lane, bf));
    Y[base + lane + 64] = f2bf((x1 - mu) * rs * loadf(gain, lane + 64, bf) + loadf(beta, lane + 64, bf));
}

// ---------------- MFMA GEMM: C = act(A @ Wt^T + bias) -----------------------
// A bf16 [M,K] row-major; Wt bf16 [Ncol,K] (pre-transposed); C fp32 or bf16.
// LDS-free, barrier-free: each wave owns a 16-row x 64-col strip.
// act: 0 none, 1 phi(elu+1), 2 gelu(exact).
__global__ __launch_bounds__(256) void mfma_gemm_kernel(
    const u16* __restrict__ A, const u16* __restrict__ Wt,
    const void* __restrict__ bias, const int* __restrict__ flags,
    void* __restrict__ C, int M, int K, int Ncol, int act, int out_bf)
{
    int wave = threadIdx.x >> 6, lane = threadIdx.x & 63;
    int quad = lane >> 4, l15 = lane & 15;
    int m0 = blockIdx.y * 64 + wave * 16;
    int n0 = blockIdx.x * 64;
    f32x4 acc[4] = {};
    const u16* ap = A + (size_t)(m0 + l15) * K + quad * 8;
    const u16* bp = Wt + (size_t)(n0 + l15) * K + quad * 8;
    for (int k0 = 0; k0 < K; k0 += 32) {
        bf16x8 a = *(const bf16x8*)(ap + k0);
        #pragma unroll
        for (int t = 0; t < 4; ++t) {
            bf16x8 b = *(const bf16x8*)(bp + (size_t)(t * 16) * K + k0);
            acc[t] = __builtin_amdgcn_mfma_f32_16x16x32_bf16(a, b, acc[t], 0, 0, 0);
        }
    }
    const int bf = flags[0];
    #pragma unroll
    for (int t = 0; t < 4; ++t) {
        int col = n0 + t * 16 + l15;
        float bv = bias ? loadf(bias, col, bf) : 0.0f;
        #pragma unroll
        for (int rg = 0; rg < 4; ++rg) {
            int row = m0 + quad * 4 + rg;
            float v = acc[t][rg] + bv;
            if (act == 1) v = (v > 0.0f) ? v + 1.0f : expf(v);
            else if (act == 2) v = 0.5f * v * (1.0f + erff(v * 0.70710678118f));
            if (out_bf) ((u16*)C)[(size_t)row * Ncol + col] = f2bf(v);
            else        ((float*)C)[(size_t)row * Ncol + col] = v;
        }
    }
}

// -------- Fused edge pipeline (MFMA, LDS-free): ------------------------------
// per wave: 16 edges x 64 cols (4 head-tiles). One k-loop feeds BOTH
// Wkr and Wvr MFMAs from a shared A fragment of rn_bf. Then:
//   phik = phi(acck + kb[src]);  p[e,h] = butterfly16(phik * phiq[dst])
//   den[dst,h] += p;  num[dst,col] += p * (accv + vb[src])
__global__ __launch_bounds__(256) void edge_mfma_kernel(
    const u16* __restrict__ rn, const u16* __restrict__ Wkrt, const u16* __restrict__ Wvrt,
    const int* __restrict__ src, const int* __restrict__ dst,
    const float* __restrict__ kb, const float* __restrict__ vb,
    const float* __restrict__ phiq,
    float* __restrict__ num, float* __restrict__ den)
{
    int wave = threadIdx.x >> 6, lane = threadIdx.x & 63;
    int quad = lane >> 4, l15 = lane & 15;
    int e0 = blockIdx.x * 32 + (wave >> 1) * 16;
    int c0 = (wave & 1) * 64;
    f32x4 acck[4] = {};
    f32x4 accv[4] = {};
    const u16* ap  = rn   + (size_t)(e0 + l15) * 128 + quad * 8;
    const u16* bkp = Wkrt + (size_t)(c0 + l15) * 128 + quad * 8;
    const u16* bvp = Wvrt + (size_t)(c0 + l15) * 128 + quad * 8;
    #pragma unroll
    for (int k0 = 0; k0 < 128; k0 += 32) {
        bf16x8 a = *(const bf16x8*)(ap + k0);
        #pragma unroll
        for (int t = 0; t < 4; ++t) {
            bf16x8 bk = *(const bf16x8*)(bkp + (size_t)(t * 16) * 128 + k0);
            bf16x8 bv = *(const bf16x8*)(bvp + (size_t)(t * 16) * 128 + k0);
            acck[t] = __builtin_amdgcn_mfma_f32_16x16x32_bf16(a, bk, acck[t], 0, 0, 0);
            accv[t] = __builtin_amdgcn_mfma_f32_16x16x32_bf16(a, bv, accv[t], 0, 0, 0);
        }
    }
    int se[4], de[4];
    #pragma unroll
    for (int rg = 0; rg < 4; ++rg) {
        int e = e0 + quad * 4 + rg;
        se[rg] = src[e]; de[rg] = dst[e];
    }
    float p[4][4];
    #pragma unroll
    for (int t = 0; t < 4; ++t) {
        int col = c0 + t * 16 + l15;
        #pragma unroll
        for (int rg = 0; rg < 4; ++rg) {
            float kv = acck[t][rg] + kb[(size_t)se[rg] * 128 + col];
            kv = (kv > 0.0f) ? kv + 1.0f : expf(kv);
            float pm = kv * phiq[(size_t)de[rg] * 128 + col];
            pm += __shfl_xor(pm, 1, 64);
            pm += __shfl_xor(pm, 2, 64);
            pm += __shfl_xor(pm, 4, 64);
            pm += __shfl_xor(pm, 8, 64);
            p[t][rg] = pm;
        }
        if (l15 == 0) {
            int h = (c0 >> 4) + t;
            #pragma unroll
            for (int rg = 0; rg < 4; ++rg)
                atomicAdd(&den[de[rg] * 8 + h], p[t][rg]);
        }
    }
    #pragma unroll
    for (int t = 0; t < 4; ++t) {
        int col = c0 + t * 16 + l15;
        #pragma unroll
        for (int rg = 0; rg < 4; ++rg) {
            float vv = accv[t][rg] + vb[(size_t)se[rg] * 128 + col];
            atomicAdd(&num[(size_t)de[rg] * 128 + col], p[t][rg] * vv);
        }
    }
}

// ---------------- Normalize: att_bf = bf16(num / max(den,1e-6)) -------------
__global__ void normalize_kernel(const float* __restrict__ num, const float* __restrict__ den,
                                 u16* __restrict__ att)
{
    int idx = blockIdx.x * 256 + threadIdx.x; // N*128
    int n = idx >> 7, h = (idx >> 4) & 7;
    float dd = fmaxf(den[n * 8 + h], 1e-6f);
    att[idx] = f2bf(num[idx] / dd);
}

// ---------------- Concat [out | xs] -> cc_bf [N,256] ------------------------
__global__ void concat_kernel(const float* __restrict__ outp, const u16* __restrict__ xs,
                              u16* __restrict__ cc)
{
    int idx = blockIdx.x * 256 + threadIdx.x; // N*256
    int n = idx >> 8, j = idx & 255;
    cc[idx] = (j < 128) ? f2bf(outp[(size_t)n * 128 + j]) : xs[(size_t)n * 128 + (j - 128)];
}

// ------- Gate + post-LN + residual: xmid = x + LN(out + sig(g)*(s-out)) -----
__global__ __launch_bounds__(256) void gate_post_kernel(const float* __restrict__ outp,
                                                        const float* __restrict__ gpre,
                                                        const float* __restrict__ sbuf,
                                                        const void* __restrict__ x,
                                                        const void* __restrict__ gain,
                                                        const void* __restrict__ beta,
                                                        const int* __restrict__ flags,
                                                        float* __restrict__ xmid)
{
    const int bf = flags[0];
    int row = blockIdx.x * 4 + (threadIdx.x >> 6);
    int lane = threadIdx.x & 63;
    size_t base = (size_t)row * 128;
    float o0 = outp[base + lane], o1 = outp[base + lane + 64];
    float sg0 = 1.0f / (1.0f + expf(-gpre[base + lane]));
    float sg1 = 1.0f / (1.0f + expf(-gpre[base + lane + 64]));
    float a0 = o0 + sg0 * (sbuf[base + lane] - o0);
    float a1 = o1 + sg1 * (sbuf[base + lane + 64] - o1);
    float s = a0 + a1, sq = a0 * a0 + a1 * a1;
    for (int m = 1; m < 64; m <<= 1) { s += __shfl_xor(s, m, 64); sq += __shfl_xor(sq, m, 64); }
    float mu = s * (1.0f / 128.0f);
    float var = sq * (1.0f / 128.0f) - mu * mu;
    float rs = rsqrtf(var + 1e-5f);
    xmid[base + lane]      = loadf(x, base + lane, bf)      + (a0 - mu) * rs * loadf(gain, lane, bf)      + loadf(beta, lane, bf);
    xmid[base + lane + 64] = loadf(x, base + lane + 64, bf) + (a1 - mu) * rs * loadf(gain, lane + 64, bf) + loadf(beta, lane + 64, bf);
}

// ---------------- Final: out = (bf16|fp32)(xmid + LN(h2)) -------------------
__global__ __launch_bounds__(256) void final_kernel(const float* __restrict__ h2,
                                                    const float* __restrict__ xmid,
                                                    const void* __restrict__ gain,
                                                    const void* __restrict__ beta,
                                                    const int* __restrict__ flags,
                                                    void* __restrict__ outp)
{
    const int bf = flags[0];
    int row = blockIdx.x * 4 + (threadIdx.x >> 6);
    int lane = threadIdx.x & 63;
    size_t base = (size_t)row * 128;
    float x0 = h2[base + lane], x1 = h2[base + lane + 64];
    float s = x0 + x1, sq = x0 * x0 + x1 * x1;
    for (int m = 1; m < 64; m <<= 1) { s += __shfl_xor(s, m, 64); sq += __shfl_xor(sq, m, 64); }
    float mu = s * (1.0f / 128.0f);
    float var = sq * (1.0f / 128.0f) - mu * mu;
    float rs = rsqrtf(var + 1e-5f);
    float y0 = xmid[base + lane]      + (x0 - mu) * rs * loadf(gain, lane, bf)      + loadf(beta, lane, bf);
    float y1 = xmid[base + lane + 64] + (x1 - mu) * rs * loadf(gain, lane + 64, bf) + loadf(beta, lane + 64, bf);
    if (bf) {
        ((u16*)outp)[base + lane]      = f2bf(y0);
        ((u16*)outp)[base + lane + 64] = f2bf(y1);
    } else {
        ((float*)outp)[base + lane]      = y0;
        ((float*)outp)[base + lane + 64] = y1;
    }
}

__global__ void zero_kernel(float* __restrict__ p, size_t n)
{
    size_t i = (size_t)blockIdx.x * 256 + threadIdx.x;
    if (i < n) p[i] = 0.0f;
}

extern "C" void kernel_launch(void* const* d_in, const int* in_sizes, int n_in,
                              void* d_out, int out_size, void* d_ws, size_t ws_size,
                              hipStream_t stream)
{
    const int N = NN, E = NE;
    const void* x       = d_in[0];
    const void* r       = d_in[1];
    const int*  ei      = (const int*)d_in[2];
    const void* ln_x_g  = d_in[3];
    const void* ln_x_b  = d_in[4];
    const void* ln_r_g  = d_in[5];
    const void* ln_r_b  = d_in[6];
    const void* ln_po_g = d_in[7];
    const void* ln_po_b = d_in[8];
    const void* ln_fp_g = d_in[9];
    const void* ln_fp_b = d_in[10];
    const void* ln_fo_g = d_in[11];
    const void* ln_fo_b = d_in[12];
    const void* Wq      = d_in[13];
    const void* Wk      = d_in[14];
    const void* Wv      = d_in[15];
    const void* Wkr     = d_in[16];
    const void* Wvr     = d_in[17];
    const void* Wo      = d_in[18];
    const void* Wg      = d_in[19];
    const void* bg      = d_in[20];
    const void* Ws      = d_in[21];
    const void* bs      = d_in[22];
    const void* W1      = d_in[23];
    const void* b1      = d_in[24];
    const void* W2      = d_in[25];
    const void* b2      = d_in[26];

    // ---- workspace, ~88.5 MB ----
    float* ws = (float*)d_ws;
    size_t off = 0;
    auto alloc = [&](size_t n) { float* p = ws + off; off += n; return p; };
    const size_t U = (size_t)N * 64;                 // 1 unit = N*128 bf16 = N*64 f32 words
    u16*   xs_bf = (u16*)alloc(U);                   // LN(x), bf16
    float* ovl   = alloc(14 * U);                    // overlay region
    float* num   = alloc((size_t)N * 128);
    float* den   = alloc((size_t)N * 8);             // contiguous after num
    float* xmid  = alloc((size_t)N * 128);
    float* h2    = alloc((size_t)N * 128);
    int*   e32   = (int*)alloc((size_t)2 * E / 1 * 1 / 2 + E); // 2E ints = E words... (see below)
    // NOTE: 2E ints == E*2*4 bytes == 2E words? ints==words. Redo cleanly:
    off -= ((size_t)2 * E / 2 + E);                  // undo
    e32          = (int*)alloc((size_t)2 * E);       // 2E int words
    int*   flags = (int*)alloc(16);
    u16*   wt    = (u16*)alloc(139264);              // 278528 bf16 transposed weights

    // phase A (pre-edge) overlay members
    u16*   rn_bf = (u16*)ovl;                        // E*128 bf16 = 8 units
    float* phiq  = ovl + 8 * U;                      // 2 units
    float* kb    = ovl + 10 * U;                     // 2 units
    float* vb    = ovl + 12 * U;                     // 2 units
    // phase B (post-edge) overlay members
    u16*   att_bf = (u16*)ovl;                       // 1 unit
    float* outp   = ovl + 1 * U;                     // 2
    float* sbuf   = ovl + 3 * U;                     // 2
    float* gpre   = ovl + 5 * U;                     // 2
    u16*   cc_bf  = (u16*)(ovl + 7 * U);             // 2
    u16*   ffp_bf = (u16*)(ovl + 9 * U);             // 1
    u16*   h1_bf  = (u16*)(ovl + 10 * U);            // 4

    // transposed-weight sub-buffers
    u16* Wq_t  = wt;                 // 128x128
    u16* Wk_t  = wt + 16384;
    u16* Wv_t  = wt + 32768;
    u16* Wkr_t = wt + 49152;
    u16* Wvr_t = wt + 65536;
    u16* Wo_t  = wt + 81920;
    u16* Ws_t  = wt + 98304;
    u16* Wg_t  = wt + 114688;        // [128][256]
    u16* W1_t  = wt + 147456;        // [512][128]
    u16* W2_t  = wt + 212992;        // [128][512]

    const int* src = e32;
    const int* dst = e32 + E;

    // 0. detection + conversions
    dtype_detect_kernel<<<1, 256, 0, stream>>>((const u16*)x, flags);
    edetect_kernel<<<1, 256, 0, stream>>>(ei, flags);
    cvt_edges_kernel<<<(2 * E + 255) / 256, 256, 0, stream>>>(ei, flags, e32);

    WTArgs wa;
    int t0 = 0;
    auto setw = [&](int i, const void* w, u16* wtp, int K, int Ncol) {
        wa.d[i] = WDesc{w, wtp, K, Ncol, t0};
        t0 += (K / 32) * (Ncol / 32);
    };
    setw(0, Wq, Wq_t, 128, 128);
    setw(1, Wk, Wk_t, 128, 128);
    setw(2, Wv, Wv_t, 128, 128);
    setw(3, Wkr, Wkr_t, 128, 128);
    setw(4, Wvr, Wvr_t, 128, 128);
    setw(5, Wo, Wo_t, 128, 128);
    setw(6, Ws, Ws_t, 128, 128);
    setw(7, Wg, Wg_t, 256, 128);
    setw(8, W1, W1_t, 128, 512);
    setw(9, W2, W2_t, 512, 128);
    wtrans_kernel<<<t0, 256, 0, stream>>>(wa, flags);

    // 1. pre-norms -> bf16
    ln_in_kernel<<<N / 4, 256, 0, stream>>>(x, ln_x_g, ln_x_b, flags, xs_bf, N);
    ln_in_kernel<<<E / 4, 256, 0, stream>>>(r, ln_r_g, ln_r_b, flags, rn_bf, E);

    // 2. node projections (phi fused into q)
    mfma_gemm_kernel<<<dim3(2, N / 64), 256, 0, stream>>>(xs_bf, Wq_t, nullptr, flags, phiq, N, 128, 128, 1, 0);
    mfma_gemm_kernel<<<dim3(2, N / 64), 256, 0, stream>>>(xs_bf, Wk_t, nullptr, flags, kb,   N, 128, 128, 0, 0);
    mfma_gemm_kernel<<<dim3(2, N / 64), 256, 0, stream>>>(xs_bf, Wv_t, nullptr, flags, vb,   N, 128, 128, 0, 0);

    // 3. zero accumulators
    {
        size_t nz = (size_t)N * 128 + (size_t)N * 8;
        zero_kernel<<<(unsigned)((nz + 255) / 256), 256, 0, stream>>>(num, nz);
    }

    // 4. fused edge pipeline
    edge_mfma_kernel<<<E / 32, 256, 0, stream>>>(rn_bf, Wkr_t, Wvr_t, src, dst,
                                                 kb, vb, phiq, num, den);

    // 5. normalize -> bf16
    normalize_kernel<<<(N * 128) / 256, 256, 0, stream>>>(num, den, att_bf);

    // 6. output projection + gate
    mfma_gemm_kernel<<<dim3(2, N / 64), 256, 0, stream>>>(att_bf, Wo_t, nullptr, flags, outp, N, 128, 128, 0, 0);
    mfma_gemm_kernel<<<dim3(2, N / 64), 256, 0, stream>>>(xs_bf, Ws_t, bs, flags, sbuf, N, 128, 128, 0, 0);
    concat_kernel<<<(N * 256) / 256, 256, 0, stream>>>(outp, xs_bf, cc_bf);
    mfma_gemm_kernel<<<dim3(2, N / 64), 256, 0, stream>>>(cc_bf, Wg_t, bg, flags, gpre, N, 256, 128, 0, 0);
    gate_post_kernel<<<N / 4, 256, 0, stream>>>(outp, gpre, sbuf, x, ln_po_g, ln_po_b, flags, xmid);

    // 7. feed-forward
    ln_mid_kernel<<<N / 4, 256, 0, stream>>>(xmid, ln_fp_g, ln_fp_b, flags, ffp_bf);
    mfma_gemm_kernel<<<dim3(8, N / 64), 256, 0, stream>>>(ffp_bf, W1_t, b1, flags, h1_bf, N, 128, 512, 2, 1);
    mfma_gemm_kernel<<<dim3(2, N / 64), 256, 0, stream>>>(h1_bf, W2_t, b2, flags, h2, N, 512, 128, 0, 0);

    // 8. final residual + LN -> out
    final_kernel<<<N / 4, 256, 0, stream>>>(h2, xmid, ln_fo_g, ln_fo_b, flags, d_out);
}

// Round 5
// 508.789 us; speedup vs baseline: 1.5929x; 1.0634x over previous
//
#include <hip/hip_runtime.h>
#include <hip/hip_bf16.h>

#define NN 16000
#define NE 128000

typedef unsigned short u16;
typedef __attribute__((ext_vector_type(8))) short bf16x8;
typedef __attribute__((ext_vector_type(4))) float f32x4;

__device__ __forceinline__ float bf2f(u16 u) {
    unsigned int v = ((unsigned int)u) << 16;
    return __uint_as_float(v);
}
__device__ __forceinline__ u16 f2bf(float f) {
    unsigned int u = __float_as_uint(f);
    unsigned int r = u + 0x7FFF + ((u >> 16) & 1);
    return (u16)(r >> 16);
}
__device__ __forceinline__ float loadf(const void* p, size_t i, int bf) {
    return bf ? bf2f(((const u16*)p)[i]) : ((const float*)p)[i];
}

// ---- dtype detect: bf16 (1) vs fp32 (0) ------------------------------------
__global__ void dtype_detect_kernel(const u16* __restrict__ xw, int* __restrict__ flags)
{
    __shared__ int cnt[256];
    int c = 0;
    for (int k = 0; k < 16; ++k) {
        unsigned int w = xw[threadIdx.x + k * 256];
        int e = (int)((w >> 7) & 0xFF);
        c += (e >= 100 && e <= 140) ? 1 : 0;
    }
    cnt[threadIdx.x] = c;
    __syncthreads();
    for (int s = 128; s > 0; s >>= 1) {
        if (threadIdx.x < s) cnt[threadIdx.x] += cnt[threadIdx.x + s];
        __syncthreads();
    }
    if (threadIdx.x == 0) flags[0] = (cnt[0] >= 3300) ? 1 : 0;
}

// ---- edge_index dtype detect (int64 vs int32): flags[1]=1 -> int64 ---------
__global__ void edetect_kernel(const int* __restrict__ ei, int* __restrict__ flags)
{
    __shared__ int acc[256];
    int a = 0;
    for (int i = threadIdx.x; i < NE; i += 256) a |= ei[2 * i + 1];
    acc[threadIdx.x] = a;
    __syncthreads();
    for (int s = 128; s > 0; s >>= 1) {
        if (threadIdx.x < s) acc[threadIdx.x] |= acc[threadIdx.x + s];
        __syncthreads();
    }
    if (threadIdx.x == 0) flags[1] = (acc[0] == 0) ? 1 : 0;
}

__global__ void cvt_edges_kernel(const int* __restrict__ ei, const int* __restrict__ flags,
                                 int* __restrict__ out)
{
    int i = blockIdx.x * 256 + threadIdx.x;
    if (i >= 2 * NE) return;
    int v = flags[1] ? ei[2 * i] : ei[i];
    v = v < 0 ? 0 : (v >= NN ? NN - 1 : v);
    out[i] = v;
}

// ---- weight transpose-convert: W[K][N] -> Wt[N][K] bf16 --------------------
struct WDesc { const void* w; u16* wt; int K; int N; int tile0; };
struct WTArgs { WDesc d[10]; };
__global__ __launch_bounds__(256) void wtrans_kernel(WTArgs args, const int* __restrict__ flags)
{
    int b = blockIdx.x;
    int i = 0;
    while (i < 9 && b >= args.d[i + 1].tile0) ++i;
    WDesc de = args.d[i];
    int lt = b - de.tile0;
    int tn = de.N >> 5;
    int tk = lt / tn, tc = lt % tn;
    int bf = flags[0];
    int n = tc * 32 + (threadIdx.x & 31);
    int k = tk * 32 + ((threadIdx.x >> 5) << 2);
    u16* dp = de.wt + (size_t)n * de.K + k;
    #pragma unroll
    for (int j = 0; j < 4; ++j)
        dp[j] = f2bf(loadf(de.w, (size_t)(k + j) * de.N + n, bf));
}

// ---------------- LayerNorm: (bf16|fp32) in -> bf16 out ---------------------
__global__ __launch_bounds__(256) void ln_in_kernel(const void* __restrict__ X,
                                                    const void* __restrict__ gain,
                                                    const void* __restrict__ beta,
                                                    const int* __restrict__ flags,
                                                    u16* __restrict__ Y, int M)
{
    const int bf = flags[0];
    int row = blockIdx.x * 4 + (threadIdx.x >> 6);
    int lane = threadIdx.x & 63;
    if (row >= M) return;
    size_t base = (size_t)row * 128;
    float x0 = loadf(X, base + lane, bf);
    float x1 = loadf(X, base + lane + 64, bf);
    float s = x0 + x1, sq = x0 * x0 + x1 * x1;
    for (int m = 1; m < 64; m <<= 1) { s += __shfl_xor(s, m, 64); sq += __shfl_xor(sq, m, 64); }
    float mu = s * (1.0f / 128.0f);
    float var = sq * (1.0f / 128.0f) - mu * mu;
    float rs = rsqrtf(var + 1e-5f);
    Y[base + lane]      = f2bf((x0 - mu) * rs * loadf(gain, lane, bf)      + loadf(beta, lane, bf));
    Y[base + lane + 64] = f2bf((x1 - mu) * rs * loadf(gain, lane + 64, bf) + loadf(beta, lane + 64, bf));
}

// ---------------- MFMA GEMM: C = act(A @ Wt^T + bias) -----------------------
// A bf16 [M,K]; Wt bf16 [Ncol][bstride] (row n at Wt + n*bstride, k-contig).
// act: 0 none, 1 phi, 2 gelu, 3 phi-if-col<128 (for fused qkv).
__global__ __launch_bounds__(256) void mfma_gemm_kernel(
    const u16* __restrict__ A, const u16* __restrict__ Wt, int bstride,
    const void* __restrict__ bias, const int* __restrict__ flags,
    void* __restrict__ C, int M, int K, int Ncol, int act, int out_bf)
{
    int wave = threadIdx.x >> 6, lane = threadIdx.x & 63;
    int quad = lane >> 4, l15 = lane & 15;
    int m0 = blockIdx.y * 64 + wave * 16;
    int n0 = blockIdx.x * 64;
    f32x4 acc[4] = {};
    const u16* ap = A + (size_t)(m0 + l15) * K + quad * 8;
    const u16* bp = Wt + (size_t)(n0 + l15) * bstride + quad * 8;
    for (int k0 = 0; k0 < K; k0 += 32) {
        bf16x8 a = *(const bf16x8*)(ap + k0);
        #pragma unroll
        for (int t = 0; t < 4; ++t) {
            bf16x8 b = *(const bf16x8*)(bp + (size_t)(t * 16) * bstride + k0);
            acc[t] = __builtin_amdgcn_mfma_f32_16x16x32_bf16(a, b, acc[t], 0, 0, 0);
        }
    }
    const int bf = flags[0];
    #pragma unroll
    for (int t = 0; t < 4; ++t) {
        int col = n0 + t * 16 + l15;
        float bv = bias ? loadf(bias, col, bf) : 0.0f;
        #pragma unroll
        for (int rg = 0; rg < 4; ++rg) {
            int row = m0 + quad * 4 + rg;
            float v = acc[t][rg] + bv;
            if (act == 1 || (act == 3 && col < 128)) v = (v > 0.0f) ? v + 1.0f : expf(v);
            else if (act == 2) v = 0.5f * v * (1.0f + erff(v * 0.70710678118f));
            if (out_bf) ((u16*)C)[(size_t)row * Ncol + col] = f2bf(v);
            else        ((float*)C)[(size_t)row * Ncol + col] = v;
        }
    }
}

// -------- Edge mega: LN(r) in-reg -> dual MFMA -> phi/dot -> scatter --------
// qkv: [N,384] bf16 = [phi(q) | k | v]
__global__ __launch_bounds__(256) void edge_mega_kernel(
    const void* __restrict__ r,
    const void* __restrict__ lng, const void* __restrict__ lnb,
    const u16* __restrict__ Wkrt, const u16* __restrict__ Wvrt,
    const int* __restrict__ src, const int* __restrict__ dst,
    const u16* __restrict__ qkv, const int* __restrict__ flags,
    float* __restrict__ num, float* __restrict__ den)
{
    const int bf = flags[0];
    __shared__ float sg[128], sb[128];
    int tid = threadIdx.x;
    if (tid < 128) { sg[tid] = loadf(lng, tid, bf); sb[tid] = loadf(lnb, tid, bf); }
    __syncthreads();
    int wave = tid >> 6, lane = tid & 63;
    int quad = lane >> 4, l15 = lane & 15;
    int e0 = blockIdx.x * 32 + (wave >> 1) * 16;
    int c0 = (wave & 1) * 64;

    // LN(r) rows in registers: lane holds cols {kc*32+quad*8 .. +7}, kc=0..3
    float vbuf[32];
    float s = 0.f, sq = 0.f;
    size_t rbase = (size_t)(e0 + l15) * 128;
    #pragma unroll
    for (int kc = 0; kc < 4; ++kc) {
        int cb = kc * 32 + quad * 8;
        if (bf) {
            ushort4 p0 = *(const ushort4*)((const u16*)r + rbase + cb);
            ushort4 p1 = *(const ushort4*)((const u16*)r + rbase + cb + 4);
            vbuf[kc*8+0]=bf2f(p0.x); vbuf[kc*8+1]=bf2f(p0.y); vbuf[kc*8+2]=bf2f(p0.z); vbuf[kc*8+3]=bf2f(p0.w);
            vbuf[kc*8+4]=bf2f(p1.x); vbuf[kc*8+5]=bf2f(p1.y); vbuf[kc*8+6]=bf2f(p1.z); vbuf[kc*8+7]=bf2f(p1.w);
        } else {
            float4 p0 = *(const float4*)((const float*)r + rbase + cb);
            float4 p1 = *(const float4*)((const float*)r + rbase + cb + 4);
            vbuf[kc*8+0]=p0.x; vbuf[kc*8+1]=p0.y; vbuf[kc*8+2]=p0.z; vbuf[kc*8+3]=p0.w;
            vbuf[kc*8+4]=p1.x; vbuf[kc*8+5]=p1.y; vbuf[kc*8+6]=p1.z; vbuf[kc*8+7]=p1.w;
        }
        #pragma unroll
        for (int j = 0; j < 8; ++j) { s += vbuf[kc*8+j]; sq += vbuf[kc*8+j]*vbuf[kc*8+j]; }
    }
    s += __shfl_xor(s, 16, 64); sq += __shfl_xor(sq, 16, 64);
    s += __shfl_xor(s, 32, 64); sq += __shfl_xor(sq, 32, 64);
    float mu = s * (1.0f / 128.0f);
    float var = sq * (1.0f / 128.0f) - mu * mu;
    float rsx = rsqrtf(var + 1e-5f);
    bf16x8 afr[4];
    #pragma unroll
    for (int kc = 0; kc < 4; ++kc) {
        bf16x8 a;
        #pragma unroll
        for (int j = 0; j < 8; ++j) {
            int col = kc * 32 + quad * 8 + j;
            a[j] = (short)f2bf((vbuf[kc*8+j] - mu) * rsx * sg[col] + sb[col]);
        }
        afr[kc] = a;
    }

    // dual MFMA over shared A fragments
    f32x4 acck[4] = {};
    f32x4 accv[4] = {};
    #pragma unroll
    for (int kc = 0; kc < 4; ++kc) {
        int k0 = kc * 32;
        #pragma unroll
        for (int t = 0; t < 4; ++t) {
            const u16* bkp = Wkrt + (size_t)(c0 + t*16 + l15) * 128 + k0 + quad * 8;
            const u16* bvp = Wvrt + (size_t)(c0 + t*16 + l15) * 128 + k0 + quad * 8;
            bf16x8 bk = *(const bf16x8*)bkp;
            bf16x8 bv = *(const bf16x8*)bvp;
            acck[t] = __builtin_amdgcn_mfma_f32_16x16x32_bf16(afr[kc], bk, acck[t], 0, 0, 0);
            accv[t] = __builtin_amdgcn_mfma_f32_16x16x32_bf16(afr[kc], bv, accv[t], 0, 0, 0);
        }
    }

    int se[4], de[4];
    #pragma unroll
    for (int rg = 0; rg < 4; ++rg) {
        int e = e0 + quad * 4 + rg;
        se[rg] = src[e]; de[rg] = dst[e];
    }
    #pragma unroll
    for (int t = 0; t < 4; ++t) {
        int col = c0 + t * 16 + l15;
        float p_[4];
        #pragma unroll
        for (int rg = 0; rg < 4; ++rg) {
            float kv = acck[t][rg] + bf2f(qkv[(size_t)se[rg] * 384 + 128 + col]);
            kv = (kv > 0.0f) ? kv + 1.0f : expf(kv);
            float pm = kv * bf2f(qkv[(size_t)de[rg] * 384 + col]);
            pm += __shfl_xor(pm, 1, 64);
            pm += __shfl_xor(pm, 2, 64);
            pm += __shfl_xor(pm, 4, 64);
            pm += __shfl_xor(pm, 8, 64);
            p_[rg] = pm;
        }
        if (l15 == 0) {
            int h = col >> 4;
            #pragma unroll
            for (int rg = 0; rg < 4; ++rg)
                atomicAdd(&den[de[rg] * 8 + h], p_[rg]);
        }
        #pragma unroll
        for (int rg = 0; rg < 4; ++rg) {
            float vv = accv[t][rg] + bf2f(qkv[(size_t)se[rg] * 384 + 256 + col]);
            atomicAdd(&num[(size_t)de[rg] * 128 + col], p_[rg] * vv);
        }
    }
}

// -------- Gate mega: att=num/den -> @Wo -> @Wg1 (+gxs) -> gate -> post-LN ----
//          -> xmid (fp32) and ffp = bf16(LN_ffpre(xmid))
__global__ __launch_bounds__(256) void gate_mega_kernel(
    const float* __restrict__ num, const float* __restrict__ den,
    const u16* __restrict__ Wo_t, const u16* __restrict__ Wg_t,   // Wg_t: [128][256]
    const float* __restrict__ gxs, const float* __restrict__ sbuf,
    const void* __restrict__ x,
    const void* __restrict__ g_po, const void* __restrict__ b_po,
    const void* __restrict__ g_fp, const void* __restrict__ b_fp,
    const int* __restrict__ flags,
    float* __restrict__ xmid, u16* __restrict__ ffp)
{
    const int bf = flags[0];
    __shared__ float lds[4][16][132];
    __shared__ float sgpo[128], sbpo[128], sgfp[128], sbfp[128];
    int tid = threadIdx.x;
    if (tid < 128) {
        sgpo[tid] = loadf(g_po, tid, bf);
        sbpo[tid] = loadf(b_po, tid, bf);
        sgfp[tid] = loadf(g_fp, tid, bf);
        sbfp[tid] = loadf(b_fp, tid, bf);
    }
    __syncthreads();
    int wave = tid >> 6, lane = tid & 63;
    int quad = lane >> 4, l15 = lane & 15;
    int m0 = blockIdx.x * 64 + wave * 16;

    // att A-fragments (normalize fused)
    bf16x8 afr[4];
    {
        int arow = m0 + l15;
        const float* np = num + (size_t)arow * 128;
        const float* dp = den + arow * 8;
        #pragma unroll
        for (int kc = 0; kc < 4; ++kc) {
            int cb = kc * 32 + quad * 8;            // cb mod 16 in {0,8} -> single head
            float inv = 1.0f / fmaxf(dp[cb >> 4], 1e-6f);
            float4 v0 = *(const float4*)(np + cb);
            float4 v1 = *(const float4*)(np + cb + 4);
            bf16x8 a;
            a[0]=(short)f2bf(v0.x*inv); a[1]=(short)f2bf(v0.y*inv);
            a[2]=(short)f2bf(v0.z*inv); a[3]=(short)f2bf(v0.w*inv);
            a[4]=(short)f2bf(v1.x*inv); a[5]=(short)f2bf(v1.y*inv);
            a[6]=(short)f2bf(v1.z*inv); a[7]=(short)f2bf(v1.w*inv);
            afr[kc] = a;
        }
    }
    // outp = att @ Wo
    f32x4 acco[8] = {};
    #pragma unroll
    for (int kc = 0; kc < 4; ++kc)
        #pragma unroll
        for (int t = 0; t < 8; ++t) {
            bf16x8 b = *(const bf16x8*)(Wo_t + (size_t)(t*16 + l15) * 128 + kc*32 + quad*8);
            acco[t] = __builtin_amdgcn_mfma_f32_16x16x32_bf16(afr[kc], b, acco[t], 0, 0, 0);
        }
    // C-layout -> LDS -> A-layout (bf16)
    #pragma unroll
    for (int t = 0; t < 8; ++t)
        #pragma unroll
        for (int rg = 0; rg < 4; ++rg)
            lds[wave][quad*4+rg][t*16+l15] = acco[t][rg];
    __syncthreads();
    bf16x8 afo[4];
    #pragma unroll
    for (int kc = 0; kc < 4; ++kc) {
        bf16x8 a;
        #pragma unroll
        for (int j = 0; j < 8; ++j)
            a[j] = (short)f2bf(lds[wave][l15][kc*32 + quad*8 + j]);
        afo[kc] = a;
    }
    // gpre_part = outp @ Wg1  (Wg_t row stride 256, k in [0,128))
    f32x4 accg[8] = {};
    #pragma unroll
    for (int kc = 0; kc < 4; ++kc)
        #pragma unroll
        for (int t = 0; t < 8; ++t) {
            bf16x8 b = *(const bf16x8*)(Wg_t + (size_t)(t*16 + l15) * 256 + kc*32 + quad*8);
            accg[t] = __builtin_amdgcn_mfma_f32_16x16x32_bf16(afo[kc], b, accg[t], 0, 0, 0);
        }
    // gate + post-LN
    float attn[8][4];
    float sv[4] = {0,0,0,0}, sqv[4] = {0,0,0,0};
    #pragma unroll
    for (int t = 0; t < 8; ++t) {
        int col = t * 16 + l15;
        #pragma unroll
        for (int rg = 0; rg < 4; ++rg) {
            int row = m0 + quad * 4 + rg;
            float gp = accg[t][rg] + gxs[(size_t)row * 128 + col];
            float gg = 1.0f / (1.0f + expf(-gp));
            float o = acco[t][rg];
            float a = o + gg * (sbuf[(size_t)row * 128 + col] - o);
            attn[t][rg] = a; sv[rg] += a; sqv[rg] += a * a;
        }
    }
    #pragma unroll
    for (int rg = 0; rg < 4; ++rg)
        for (int m = 1; m < 16; m <<= 1) {
            sv[rg] += __shfl_xor(sv[rg], m, 64);
            sqv[rg] += __shfl_xor(sqv[rg], m, 64);
        }
    float mu[4], rs[4];
    #pragma unroll
    for (int rg = 0; rg < 4; ++rg) {
        mu[rg] = sv[rg] * (1.0f / 128.0f);
        float var = sqv[rg] * (1.0f / 128.0f) - mu[rg] * mu[rg];
        rs[rg] = rsqrtf(var + 1e-5f);
    }
    // xmid = x + LN(attn); second LN -> ffp
    float s2[4] = {0,0,0,0}, sq2[4] = {0,0,0,0};
    #pragma unroll
    for (int t = 0; t < 8; ++t) {
        int col = t * 16 + l15;
        #pragma unroll
        for (int rg = 0; rg < 4; ++rg) {
            int row = m0 + quad * 4 + rg;
            float xm = loadf(x, (size_t)row * 128 + col, bf)
                     + (attn[t][rg] - mu[rg]) * rs[rg] * sgpo[col] + sbpo[col];
            attn[t][rg] = xm;
            xmid[(size_t)row * 128 + col] = xm;
            s2[rg] += xm; sq2[rg] += xm * xm;
        }
    }
    #pragma unroll
    for (int rg = 0; rg < 4; ++rg)
        for (int m = 1; m < 16; m <<= 1) {
            s2[rg] += __shfl_xor(s2[rg], m, 64);
            sq2[rg] += __shfl_xor(sq2[rg], m, 64);
        }
    #pragma unroll
    for (int rg = 0; rg < 4; ++rg) {
        float mu2 = s2[rg] * (1.0f / 128.0f);
        float var2 = sq2[rg] * (1.0f / 128.0f) - mu2 * mu2;
        float rs2 = rsqrtf(var2 + 1e-5f);
        #pragma unroll
        for (int t = 0; t < 8; ++t) {
            int col = t * 16 + l15;
            int row = m0 + quad * 4 + rg;
            ffp[(size_t)row * 128 + col] =
                f2bf((attn[t][rg] - mu2) * rs2 * sgfp[col] + sbfp[col]);
        }
    }
}

// -------- FF mega: h1=gelu(ffp@W1+b1) -> h2=h1@W2+b2 -> out=xmid+LN(h2) ------
__global__ __launch_bounds__(128) void ff_mega_kernel(
    const u16* __restrict__ ffp, const u16* __restrict__ W1_t, const void* __restrict__ b1,
    const u16* __restrict__ W2_t, const void* __restrict__ b2,
    const float* __restrict__ xmid,
    const void* __restrict__ g_fo, const void* __restrict__ b_fo,
    const int* __restrict__ flags, void* __restrict__ outp)
{
    const int bf = flags[0];
    __shared__ __align__(16) u16 h1l[2][16][520];   // pad 520: 2-way banks only
    int tid = threadIdx.x;
    int wave = tid >> 6, lane = tid & 63;
    int quad = lane >> 4, l15 = lane & 15;
    int m0 = blockIdx.x * 32 + wave * 16;

    bf16x8 afr[4];
    const u16* ap = ffp + (size_t)(m0 + l15) * 128 + quad * 8;
    #pragma unroll
    for (int kc = 0; kc < 4; ++kc) afr[kc] = *(const bf16x8*)(ap + kc * 32);

    f32x4 acc1[32] = {};
    #pragma unroll
    for (int kc = 0; kc < 4; ++kc)
        #pragma unroll
        for (int t = 0; t < 32; ++t) {
            bf16x8 b = *(const bf16x8*)(W1_t + (size_t)(t*16 + l15) * 128 + kc*32 + quad*8);
            acc1[t] = __builtin_amdgcn_mfma_f32_16x16x32_bf16(afr[kc], b, acc1[t], 0, 0, 0);
        }
    #pragma unroll
    for (int t = 0; t < 32; ++t) {
        int col = t * 16 + l15;
        float bv = loadf(b1, col, bf);
        #pragma unroll
        for (int rg = 0; rg < 4; ++rg) {
            float v = acc1[t][rg] + bv;
            v = 0.5f * v * (1.0f + erff(v * 0.70710678118f));
            h1l[wave][quad * 4 + rg][col] = f2bf(v);
        }
    }
    __syncthreads();
    f32x4 acc2[8] = {};
    #pragma unroll
    for (int kc = 0; kc < 16; ++kc) {
        bf16x8 a = *(const bf16x8*)&h1l[wave][l15][kc * 32 + quad * 8];
        #pragma unroll
        for (int t = 0; t < 8; ++t) {
            bf16x8 b = *(const bf16x8*)(W2_t + (size_t)(t*16 + l15) * 512 + kc*32 + quad*8);
            acc2[t] = __builtin_amdgcn_mfma_f32_16x16x32_bf16(a, b, acc2[t], 0, 0, 0);
        }
    }
    // final LN + residual
    float h2v[8][4];
    float sv[4] = {0,0,0,0}, sqv[4] = {0,0,0,0};
    #pragma unroll
    for (int t = 0; t < 8; ++t) {
        int col = t * 16 + l15;
        float bv = loadf(b2, col, bf);
        #pragma unroll
        for (int rg = 0; rg < 4; ++rg) {
            float v = acc2[t][rg] + bv;
            h2v[t][rg] = v; sv[rg] += v; sqv[rg] += v * v;
        }
    }
    #pragma unroll
    for (int rg = 0; rg < 4; ++rg)
        for (int m = 1; m < 16; m <<= 1) {
            sv[rg] += __shfl_xor(sv[rg], m, 64);
            sqv[rg] += __shfl_xor(sqv[rg], m, 64);
        }
    #pragma unroll
    for (int rg = 0; rg < 4; ++rg) {
        float mu = sv[rg] * (1.0f / 128.0f);
        float var = sqv[rg] * (1.0f / 128.0f) - mu * mu;
        float rs = rsqrtf(var + 1e-5f);
        int row = m0 + quad * 4 + rg;
        #pragma unroll
        for (int t = 0; t < 8; ++t) {
            int col = t * 16 + l15;
            float y = xmid[(size_t)row * 128 + col]
                    + (h2v[t][rg] - mu) * rs * loadf(g_fo, col, bf) + loadf(b_fo, col, bf);
            if (bf) ((u16*)outp)[(size_t)row * 128 + col] = f2bf(y);
            else    ((float*)outp)[(size_t)row * 128 + col] = y;
        }
    }
}

__global__ void zero_kernel(float* __restrict__ p, size_t n)
{
    size_t i = (size_t)blockIdx.x * 256 + threadIdx.x;
    if (i < n) p[i] = 0.0f;
}

extern "C" void kernel_launch(void* const* d_in, const int* in_sizes, int n_in,
                              void* d_out, int out_size, void* d_ws, size_t ws_size,
                              hipStream_t stream)
{
    const int N = NN, E = NE;
    const void* x       = d_in[0];
    const void* r       = d_in[1];
    const int*  ei      = (const int*)d_in[2];
    const void* ln_x_g  = d_in[3];
    const void* ln_x_b  = d_in[4];
    const void* ln_r_g  = d_in[5];
    const void* ln_r_b  = d_in[6];
    const void* ln_po_g = d_in[7];
    const void* ln_po_b = d_in[8];
    const void* ln_fp_g = d_in[9];
    const void* ln_fp_b = d_in[10];
    const void* ln_fo_g = d_in[11];
    const void* ln_fo_b = d_in[12];
    const void* Wq      = d_in[13];
    const void* Wk      = d_in[14];
    const void* Wv      = d_in[15];
    const void* Wkr     = d_in[16];
    const void* Wvr     = d_in[17];
    const void* Wo      = d_in[18];
    const void* Wg      = d_in[19];
    const void* bg      = d_in[20];
    const void* Ws      = d_in[21];
    const void* bs      = d_in[22];
    const void* W1      = d_in[23];
    const void* b1      = d_in[24];
    const void* W2      = d_in[25];
    const void* b2      = d_in[26];

    // ---- workspace ~55 MB ----
    float* ws = (float*)d_ws;
    size_t off = 0;
    auto alloc = [&](size_t n) { float* p = ws + off; off += n; return p; };
    const size_t U = (size_t)N * 64;
    u16*   xs_bf  = (u16*)alloc(U);            // [N,128] bf16
    u16*   qkv_bf = (u16*)alloc(3 * U);        // [N,384] bf16: phi(q)|k|v
    float* num    = alloc((size_t)N * 128);
    float* den    = alloc((size_t)N * 8);      // contiguous after num
    float* sbuf   = alloc((size_t)N * 128);
    float* gxs    = alloc((size_t)N * 128);
    float* xmid   = alloc((size_t)N * 128);
    u16*   ffp_bf = (u16*)alloc(U);
    int*   e32    = (int*)alloc((size_t)2 * E);
    int*   flags  = (int*)alloc(16);
    u16*   wt     = (u16*)alloc(139264);       // 278528 bf16

    u16* Wq_t  = wt;                 // [384][128] contiguous qkv block
    u16* Wkr_t = wt + 49152;
    u16* Wvr_t = wt + 65536;
    u16* Wo_t  = wt + 81920;
    u16* Ws_t  = wt + 98304;
    u16* Wg_t  = wt + 114688;        // [128][256]
    u16* W1_t  = wt + 147456;        // [512][128]
    u16* W2_t  = wt + 212992;        // [128][512]

    const int* src = e32;
    const int* dst = e32 + E;

    // 0. detection + conversion
    dtype_detect_kernel<<<1, 256, 0, stream>>>((const u16*)x, flags);
    edetect_kernel<<<1, 256, 0, stream>>>(ei, flags);
    cvt_edges_kernel<<<(2 * E + 255) / 256, 256, 0, stream>>>(ei, flags, e32);

    WTArgs wa;
    int t0 = 0;
    auto setw = [&](int i, const void* w, u16* wtp, int K, int Ncol) {
        wa.d[i] = WDesc{w, wtp, K, Ncol, t0};
        t0 += (K / 32) * (Ncol / 32);
    };
    setw(0, Wq, Wq_t, 128, 128);
    setw(1, Wk, wt + 16384, 128, 128);
    setw(2, Wv, wt + 32768, 128, 128);
    setw(3, Wkr, Wkr_t, 128, 128);
    setw(4, Wvr, Wvr_t, 128, 128);
    setw(5, Wo, Wo_t, 128, 128);
    setw(6, Ws, Ws_t, 128, 128);
    setw(7, Wg, Wg_t, 256, 128);
    setw(8, W1, W1_t, 128, 512);
    setw(9, W2, W2_t, 512, 128);
    wtrans_kernel<<<t0, 256, 0, stream>>>(wa, flags);

    // 1. LN(x) -> bf16
    ln_in_kernel<<<N / 4, 256, 0, stream>>>(x, ln_x_g, ln_x_b, flags, xs_bf, N);

    // 2. fused qkv GEMM: [N,384] bf16, phi on q-block
    mfma_gemm_kernel<<<dim3(6, N / 64), 256, 0, stream>>>(
        xs_bf, Wq_t, 128, nullptr, flags, qkv_bf, N, 128, 384, 3, 1);

    // 3. zero num+den
    {
        size_t nz = (size_t)N * 128 + (size_t)N * 8;
        zero_kernel<<<(unsigned)((nz + 255) / 256), 256, 0, stream>>>(num, nz);
    }

    // 4. edge mega (LN(r) fused)
    edge_mega_kernel<<<E / 32, 256, 0, stream>>>(r, ln_r_g, ln_r_b, Wkr_t, Wvr_t,
                                                 src, dst, qkv_bf, flags, num, den);

    // 5. sbuf = xs@Ws+bs ; gxs = xs@Wg2+bg  (independent of edge)
    mfma_gemm_kernel<<<dim3(2, N / 64), 256, 0, stream>>>(
        xs_bf, Ws_t, 128, bs, flags, sbuf, N, 128, 128, 0, 0);
    mfma_gemm_kernel<<<dim3(2, N / 64), 256, 0, stream>>>(
        xs_bf, Wg_t + 128, 256, bg, flags, gxs, N, 128, 128, 0, 0);

    // 6. gate mega -> xmid, ffp
    gate_mega_kernel<<<N / 64, 256, 0, stream>>>(num, den, Wo_t, Wg_t, gxs, sbuf,
                                                 x, ln_po_g, ln_po_b, ln_fp_g, ln_fp_b,
                                                 flags, xmid, ffp_bf);

    // 7. ff mega -> d_out
    ff_mega_kernel<<<N / 32, 128, 0, stream>>>(ffp_bf, W1_t, b1, W2_t, b2,
                                               xmid, ln_fo_g, ln_fo_b, flags, d_out);
}

// Round 6
// 466.011 us; speedup vs baseline: 1.7392x; 1.0918x over previous
//
#include <hip/hip_runtime.h>
#include <hip/hip_bf16.h>

#define NN 16000
#define NE 128000

typedef unsigned short u16;
typedef __attribute__((ext_vector_type(8))) short bf16x8;
typedef __attribute__((ext_vector_type(4))) float f32x4;

__device__ __forceinline__ float bf2f(u16 u) {
    unsigned int v = ((unsigned int)u) << 16;
    return __uint_as_float(v);
}
__device__ __forceinline__ u16 f2bf(float f) {
    unsigned int u = __float_as_uint(f);
    unsigned int r = u + 0x7FFF + ((u >> 16) & 1);
    return (u16)(r >> 16);
}
__device__ __forceinline__ float loadf(const void* p, size_t i, int bf) {
    return bf ? bf2f(((const u16*)p)[i]) : ((const float*)p)[i];
}

// ---- dtype detect: bf16 (1) vs fp32 (0); also zeroes flags[2] --------------
__global__ void dtype_detect_kernel(const u16* __restrict__ xw, int* __restrict__ flags)
{
    __shared__ int cnt[256];
    if (threadIdx.x == 0) flags[2] = 0;
    int c = 0;
    #pragma unroll
    for (int k = 0; k < 16; ++k) {
        unsigned int w = xw[threadIdx.x + k * 256];
        int e = (int)((w >> 7) & 0xFF);
        c += (e >= 100 && e <= 140) ? 1 : 0;
    }
    cnt[threadIdx.x] = c;
    __syncthreads();
    for (int s = 128; s > 0; s >>= 1) {
        if (threadIdx.x < s) cnt[threadIdx.x] += cnt[threadIdx.x + s];
        __syncthreads();
    }
    if (threadIdx.x == 0) flags[0] = (cnt[0] >= 3300) ? 1 : 0;
}

// ---- edge_index dtype detect, PARALLEL: OR of odd words -> flags[2] --------
// int64 layout iff flags[2] == 0 afterwards.
__global__ __launch_bounds__(256) void edetect_kernel(const int* __restrict__ ei,
                                                      int* __restrict__ flags)
{
    int t = blockIdx.x * 256 + threadIdx.x;    // 125 blocks * 256 = 32000
    int a = 0;
    #pragma unroll
    for (int j = 0; j < 4; ++j) a |= ei[2 * (t * 4 + j) + 1];
    for (int m = 1; m < 64; m <<= 1) a |= __shfl_xor(a, m, 64);
    if ((threadIdx.x & 63) == 0 && a) atomicOr(&flags[2], a);
}

// ---- convert+clamp edges; also zero histogram bins -------------------------
__global__ void cvt_edges_kernel(const int* __restrict__ ei, const int* __restrict__ flags,
                                 int* __restrict__ out, int* __restrict__ hist)
{
    int i = blockIdx.x * 256 + threadIdx.x;
    if (i < NN) hist[i] = 0;
    if (i >= 2 * NE) return;
    int v = (flags[2] == 0) ? ei[2 * i] : ei[i];
    v = v < 0 ? 0 : (v >= NN ? NN - 1 : v);
    out[i] = v;
}

// ---- histogram of dst ------------------------------------------------------
__global__ void hist_kernel(const int* __restrict__ e32, int* __restrict__ hist)
{
    int i = blockIdx.x * 256 + threadIdx.x;
    if (i < NE) atomicAdd(&hist[e32[NE + i]], 1);
}

// ---- exclusive scan of hist -> offs[NN+1], copy -> cursor ------------------
__global__ __launch_bounds__(256) void scan_kernel(const int* __restrict__ hist,
                                                   int* __restrict__ offs,
                                                   int* __restrict__ cursor)
{
    __shared__ int wsum[4];
    __shared__ int carry_s;
    int tid = threadIdx.x, lane = tid & 63, w = tid >> 6;
    if (tid == 0) { carry_s = 0; offs[0] = 0; cursor[0] = 0; }
    __syncthreads();
    for (int c0 = 0; c0 < NN; c0 += 256) {
        int i = c0 + tid;
        int x = (i < NN) ? hist[i] : 0;
        #pragma unroll
        for (int o = 1; o < 64; o <<= 1) {
            int y = __shfl_up(x, o, 64);
            if (lane >= o) x += y;
        }
        if (lane == 63) wsum[w] = x;
        __syncthreads();
        if (tid == 0) {
            int s = 0;
            #pragma unroll
            for (int j = 0; j < 4; ++j) { int t2 = wsum[j]; wsum[j] = s; s += t2; }
        }
        __syncthreads();
        int incl = x + wsum[w] + carry_s;
        if (i < NN) { offs[i + 1] = incl; cursor[i + 1] = incl; }
        __syncthreads();
        if (tid == 255) carry_s = incl;
        __syncthreads();
    }
}

// ---- scatter: dst-sorted edge order ----------------------------------------
__global__ void scatter_kernel(const int* __restrict__ e32, int* __restrict__ cursor,
                               int* __restrict__ perm, int* __restrict__ ssrc,
                               int* __restrict__ sdst)
{
    int i = blockIdx.x * 256 + threadIdx.x;
    if (i >= NE) return;
    int d = e32[NE + i];
    int pos = atomicAdd(&cursor[d], 1);
    perm[pos] = i;
    ssrc[pos] = e32[i];
    sdst[pos] = d;
}

// ---- weight transpose-convert: W[K][N] -> Wt[N][K] bf16 --------------------
struct WDesc { const void* w; u16* wt; int K; int N; int tile0; };
struct WTArgs { WDesc d[10]; };
__global__ __launch_bounds__(256) void wtrans_kernel(WTArgs args, const int* __restrict__ flags)
{
    int b = blockIdx.x;
    int i = 0;
    while (i < 9 && b >= args.d[i + 1].tile0) ++i;
    WDesc de = args.d[i];
    int lt = b - de.tile0;
    int tn = de.N >> 5;
    int tk = lt / tn, tc = lt % tn;
    int bf = flags[0];
    int n = tc * 32 + (threadIdx.x & 31);
    int k = tk * 32 + ((threadIdx.x >> 5) << 2);
    u16* dp = de.wt + (size_t)n * de.K + k;
    #pragma unroll
    for (int j = 0; j < 4; ++j)
        dp[j] = f2bf(loadf(de.w, (size_t)(k + j) * de.N + n, bf));
}

// ---------------- LayerNorm: (bf16|fp32) in -> bf16 out ---------------------
__global__ __launch_bounds__(256) void ln_in_kernel(const void* __restrict__ X,
                                                    const void* __restrict__ gain,
                                                    const void* __restrict__ beta,
                                                    const int* __restrict__ flags,
                                                    u16* __restrict__ Y, int M)
{
    const int bf = flags[0];
    int row = blockIdx.x * 4 + (threadIdx.x >> 6);
    int lane = threadIdx.x & 63;
    if (row >= M) return;
    size_t base = (size_t)row * 128;
    float x0 = loadf(X, base + lane, bf);
    float x1 = loadf(X, base + lane + 64, bf);
    float s = x0 + x1, sq = x0 * x0 + x1 * x1;
    for (int m = 1; m < 64; m <<= 1) { s += __shfl_xor(s, m, 64); sq += __shfl_xor(sq, m, 64); }
    float mu = s * (1.0f / 128.0f);
    float var = sq * (1.0f / 128.0f) - mu * mu;
    float rs = rsqrtf(var + 1e-5f);
    Y[base + lane]      = f2bf((x0 - mu) * rs * loadf(gain, lane, bf)      + loadf(beta, lane, bf));
    Y[base + lane + 64] = f2bf((x1 - mu) * rs * loadf(gain, lane + 64, bf) + loadf(beta, lane + 64, bf));
}

// ---------------- MFMA GEMM: C = act(A @ Wt^T + bias) -----------------------
__global__ __launch_bounds__(256) void mfma_gemm_kernel(
    const u16* __restrict__ A, const u16* __restrict__ Wt, int bstride,
    const void* __restrict__ bias, const int* __restrict__ flags,
    void* __restrict__ C, int M, int K, int Ncol, int act, int out_bf)
{
    int wave = threadIdx.x >> 6, lane = threadIdx.x & 63;
    int quad = lane >> 4, l15 = lane & 15;
    int m0 = blockIdx.y * 64 + wave * 16;
    int n0 = blockIdx.x * 64;
    f32x4 acc[4] = {};
    const u16* ap = A + (size_t)(m0 + l15) * K + quad * 8;
    const u16* bp = Wt + (size_t)(n0 + l15) * bstride + quad * 8;
    for (int k0 = 0; k0 < K; k0 += 32) {
        bf16x8 a = *(const bf16x8*)(ap + k0);
        #pragma unroll
        for (int t = 0; t < 4; ++t) {
            bf16x8 b = *(const bf16x8*)(bp + (size_t)(t * 16) * bstride + k0);
            acc[t] = __builtin_amdgcn_mfma_f32_16x16x32_bf16(a, b, acc[t], 0, 0, 0);
        }
    }
    const int bf = flags[0];
    #pragma unroll
    for (int t = 0; t < 4; ++t) {
        int col = n0 + t * 16 + l15;
        float bv = bias ? loadf(bias, col, bf) : 0.0f;
        #pragma unroll
        for (int rg = 0; rg < 4; ++rg) {
            int row = m0 + quad * 4 + rg;
            float v = acc[t][rg] + bv;
            if (act == 1 || (act == 3 && col < 128)) v = (v > 0.0f) ? v + 1.0f : expf(v);
            else if (act == 2) v = 0.5f * v * (1.0f + erff(v * 0.70710678118f));
            if (out_bf) ((u16*)C)[(size_t)row * Ncol + col] = f2bf(v);
            else        ((float*)C)[(size_t)row * Ncol + col] = v;
        }
    }
}

// -------- Edge proj (dst-sorted, atomic-free): LN(r[perm]) -> dual MFMA -----
//          -> phi, p=<phiq[dst],phik> -> write p[E,8], ve[E,128] coalesced
__global__ __launch_bounds__(256) void edge_proj_kernel(
    const void* __restrict__ r,
    const void* __restrict__ lng, const void* __restrict__ lnb,
    const u16* __restrict__ Wkrt, const u16* __restrict__ Wvrt,
    const int* __restrict__ perm, const int* __restrict__ ssrc,
    const int* __restrict__ sdst,
    const u16* __restrict__ qkv, const int* __restrict__ flags,
    float* __restrict__ p_arr, u16* __restrict__ ve_s)
{
    const int bf = flags[0];
    __shared__ float sg[128], sb[128];
    int tid = threadIdx.x;
    if (tid < 128) { sg[tid] = loadf(lng, tid, bf); sb[tid] = loadf(lnb, tid, bf); }
    __syncthreads();
    int wave = tid >> 6, lane = tid & 63;
    int quad = lane >> 4, l15 = lane & 15;
    int e0 = blockIdx.x * 32 + (wave >> 1) * 16;
    int c0 = (wave & 1) * 64;

    int rrow = perm[e0 + l15];
    float vbuf[32];
    float s = 0.f, sq = 0.f;
    size_t rbase = (size_t)rrow * 128;
    #pragma unroll
    for (int kc = 0; kc < 4; ++kc) {
        int cb = kc * 32 + quad * 8;
        if (bf) {
            ushort4 p0 = *(const ushort4*)((const u16*)r + rbase + cb);
            ushort4 p1 = *(const ushort4*)((const u16*)r + rbase + cb + 4);
            vbuf[kc*8+0]=bf2f(p0.x); vbuf[kc*8+1]=bf2f(p0.y); vbuf[kc*8+2]=bf2f(p0.z); vbuf[kc*8+3]=bf2f(p0.w);
            vbuf[kc*8+4]=bf2f(p1.x); vbuf[kc*8+5]=bf2f(p1.y); vbuf[kc*8+6]=bf2f(p1.z); vbuf[kc*8+7]=bf2f(p1.w);
        } else {
            float4 p0 = *(const float4*)((const float*)r + rbase + cb);
            float4 p1 = *(const float4*)((const float*)r + rbase + cb + 4);
            vbuf[kc*8+0]=p0.x; vbuf[kc*8+1]=p0.y; vbuf[kc*8+2]=p0.z; vbuf[kc*8+3]=p0.w;
            vbuf[kc*8+4]=p1.x; vbuf[kc*8+5]=p1.y; vbuf[kc*8+6]=p1.z; vbuf[kc*8+7]=p1.w;
        }
        #pragma unroll
        for (int j = 0; j < 8; ++j) { s += vbuf[kc*8+j]; sq += vbuf[kc*8+j]*vbuf[kc*8+j]; }
    }
    s += __shfl_xor(s, 16, 64); sq += __shfl_xor(sq, 16, 64);
    s += __shfl_xor(s, 32, 64); sq += __shfl_xor(sq, 32, 64);
    float mu = s * (1.0f / 128.0f);
    float var = sq * (1.0f / 128.0f) - mu * mu;
    float rsx = rsqrtf(var + 1e-5f);
    bf16x8 afr[4];
    #pragma unroll
    for (int kc = 0; kc < 4; ++kc) {
        bf16x8 a;
        #pragma unroll
        for (int j = 0; j < 8; ++j) {
            int col = kc * 32 + quad * 8 + j;
            a[j] = (short)f2bf((vbuf[kc*8+j] - mu) * rsx * sg[col] + sb[col]);
        }
        afr[kc] = a;
    }

    f32x4 acck[4] = {};
    f32x4 accv[4] = {};
    #pragma unroll
    for (int kc = 0; kc < 4; ++kc) {
        int k0 = kc * 32;
        #pragma unroll
        for (int t = 0; t < 4; ++t) {
            bf16x8 bk = *(const bf16x8*)(Wkrt + (size_t)(c0 + t*16 + l15) * 128 + k0 + quad * 8);
            bf16x8 bv = *(const bf16x8*)(Wvrt + (size_t)(c0 + t*16 + l15) * 128 + k0 + quad * 8);
            acck[t] = __builtin_amdgcn_mfma_f32_16x16x32_bf16(afr[kc], bk, acck[t], 0, 0, 0);
            accv[t] = __builtin_amdgcn_mfma_f32_16x16x32_bf16(afr[kc], bv, accv[t], 0, 0, 0);
        }
    }

    int se[4], de[4];
    #pragma unroll
    for (int rg = 0; rg < 4; ++rg) {
        int e = e0 + quad * 4 + rg;
        se[rg] = ssrc[e]; de[rg] = sdst[e];
    }
    #pragma unroll
    for (int t = 0; t < 4; ++t) {
        int col = c0 + t * 16 + l15;
        float p_[4];
        #pragma unroll
        for (int rg = 0; rg < 4; ++rg) {
            float kv = acck[t][rg] + bf2f(qkv[(size_t)se[rg] * 384 + 128 + col]);
            kv = (kv > 0.0f) ? kv + 1.0f : expf(kv);
            float pm = kv * bf2f(qkv[(size_t)de[rg] * 384 + col]);
            pm += __shfl_xor(pm, 1, 64);
            pm += __shfl_xor(pm, 2, 64);
            pm += __shfl_xor(pm, 4, 64);
            pm += __shfl_xor(pm, 8, 64);
            p_[rg] = pm;
        }
        if (l15 == 0) {
            #pragma unroll
            for (int rg = 0; rg < 4; ++rg)
                p_arr[(size_t)(e0 + quad * 4 + rg) * 8 + (c0 >> 4) + t] = p_[rg];
        }
        #pragma unroll
        for (int rg = 0; rg < 4; ++rg) {
            float vv = accv[t][rg] + bf2f(qkv[(size_t)se[rg] * 384 + 256 + col]);
            ve_s[(size_t)(e0 + quad * 4 + rg) * 128 + col] = f2bf(vv);
        }
    }
}

// -------- Node accumulate: att = (sum p*ve) / max(sum p, eps), no atomics ---
__global__ __launch_bounds__(256) void node_acc_kernel(
    const float* __restrict__ p_arr, const u16* __restrict__ ve_s,
    const int* __restrict__ offs, u16* __restrict__ att)
{
    int n = blockIdx.x * 4 + (threadIdx.x >> 6);
    int lane = threadIdx.x & 63;
    int beg = offs[n], end = offs[n + 1];
    int h0 = lane >> 4, h1 = 4 + h0;
    float n0 = 0.f, n1 = 0.f, d0 = 0.f, d1 = 0.f;
    for (int e = beg; e < end; ++e) {
        float p0 = p_arr[(size_t)e * 8 + h0];
        float p1 = p_arr[(size_t)e * 8 + h1];
        float v0 = bf2f(ve_s[(size_t)e * 128 + lane]);
        float v1 = bf2f(ve_s[(size_t)e * 128 + lane + 64]);
        n0 += p0 * v0; n1 += p1 * v1;
        d0 += p0; d1 += p1;
    }
    att[(size_t)n * 128 + lane]      = f2bf(n0 / fmaxf(d0, 1e-6f));
    att[(size_t)n * 128 + lane + 64] = f2bf(n1 / fmaxf(d1, 1e-6f));
}

// -------- Gate mega: att@Wo -> @Wg1 (+gxs) -> gate -> post-LN -> xmid, ffp ---
__global__ __launch_bounds__(256) void gate_mega_kernel(
    const u16* __restrict__ att,
    const u16* __restrict__ Wo_t, const u16* __restrict__ Wg_t,   // Wg_t: [128][256]
    const float* __restrict__ gxs, const float* __restrict__ sbuf,
    const void* __restrict__ x,
    const void* __restrict__ g_po, const void* __restrict__ b_po,
    const void* __restrict__ g_fp, const void* __restrict__ b_fp,
    const int* __restrict__ flags,
    float* __restrict__ xmid, u16* __restrict__ ffp)
{
    const int bf = flags[0];
    __shared__ float lds[4][16][132];
    __shared__ float sgpo[128], sbpo[128], sgfp[128], sbfp[128];
    int tid = threadIdx.x;
    if (tid < 128) {
        sgpo[tid] = loadf(g_po, tid, bf);
        sbpo[tid] = loadf(b_po, tid, bf);
        sgfp[tid] = loadf(g_fp, tid, bf);
        sbfp[tid] = loadf(b_fp, tid, bf);
    }
    __syncthreads();
    int wave = tid >> 6, lane = tid & 63;
    int quad = lane >> 4, l15 = lane & 15;
    int m0 = blockIdx.x * 64 + wave * 16;

    bf16x8 afr[4];
    #pragma unroll
    for (int kc = 0; kc < 4; ++kc)
        afr[kc] = *(const bf16x8*)(att + (size_t)(m0 + l15) * 128 + kc * 32 + quad * 8);

    f32x4 acco[8] = {};
    #pragma unroll
    for (int kc = 0; kc < 4; ++kc)
        #pragma unroll
        for (int t = 0; t < 8; ++t) {
            bf16x8 b = *(const bf16x8*)(Wo_t + (size_t)(t*16 + l15) * 128 + kc*32 + quad*8);
            acco[t] = __builtin_amdgcn_mfma_f32_16x16x32_bf16(afr[kc], b, acco[t], 0, 0, 0);
        }
    #pragma unroll
    for (int t = 0; t < 8; ++t)
        #pragma unroll
        for (int rg = 0; rg < 4; ++rg)
            lds[wave][quad*4+rg][t*16+l15] = acco[t][rg];
    __syncthreads();
    bf16x8 afo[4];
    #pragma unroll
    for (int kc = 0; kc < 4; ++kc) {
        bf16x8 a;
        #pragma unroll
        for (int j = 0; j < 8; ++j)
            a[j] = (short)f2bf(lds[wave][l15][kc*32 + quad*8 + j]);
        afo[kc] = a;
    }
    f32x4 accg[8] = {};
    #pragma unroll
    for (int kc = 0; kc < 4; ++kc)
        #pragma unroll
        for (int t = 0; t < 8; ++t) {
            bf16x8 b = *(const bf16x8*)(Wg_t + (size_t)(t*16 + l15) * 256 + kc*32 + quad*8);
            accg[t] = __builtin_amdgcn_mfma_f32_16x16x32_bf16(afo[kc], b, accg[t], 0, 0, 0);
        }
    float attn[8][4];
    float sv[4] = {0,0,0,0}, sqv[4] = {0,0,0,0};
    #pragma unroll
    for (int t = 0; t < 8; ++t) {
        int col = t * 16 + l15;
        #pragma unroll
        for (int rg = 0; rg < 4; ++rg) {
            int row = m0 + quad * 4 + rg;
            float gp = accg[t][rg] + gxs[(size_t)row * 128 + col];
            float gg = 1.0f / (1.0f + expf(-gp));
            float o = acco[t][rg];
            float a = o + gg * (sbuf[(size_t)row * 128 + col] - o);
            attn[t][rg] = a; sv[rg] += a; sqv[rg] += a * a;
        }
    }
    #pragma unroll
    for (int rg = 0; rg < 4; ++rg)
        for (int m = 1; m < 16; m <<= 1) {
            sv[rg] += __shfl_xor(sv[rg], m, 64);
            sqv[rg] += __shfl_xor(sqv[rg], m, 64);
        }
    float mu[4], rs[4];
    #pragma unroll
    for (int rg = 0; rg < 4; ++rg) {
        mu[rg] = sv[rg] * (1.0f / 128.0f);
        float var = sqv[rg] * (1.0f / 128.0f) - mu[rg] * mu[rg];
        rs[rg] = rsqrtf(var + 1e-5f);
    }
    float s2[4] = {0,0,0,0}, sq2[4] = {0,0,0,0};
    #pragma unroll
    for (int t = 0; t < 8; ++t) {
        int col = t * 16 + l15;
        #pragma unroll
        for (int rg = 0; rg < 4; ++rg) {
            int row = m0 + quad * 4 + rg;
            float xm = loadf(x, (size_t)row * 128 + col, bf)
                     + (attn[t][rg] - mu[rg]) * rs[rg] * sgpo[col] + sbpo[col];
            attn[t][rg] = xm;
            xmid[(size_t)row * 128 + col] = xm;
            s2[rg] += xm; sq2[rg] += xm * xm;
        }
    }
    #pragma unroll
    for (int rg = 0; rg < 4; ++rg)
        for (int m = 1; m < 16; m <<= 1) {
            s2[rg] += __shfl_xor(s2[rg], m, 64);
            sq2[rg] += __shfl_xor(sq2[rg], m, 64);
        }
    #pragma unroll
    for (int rg = 0; rg < 4; ++rg) {
        float mu2 = s2[rg] * (1.0f / 128.0f);
        float var2 = sq2[rg] * (1.0f / 128.0f) - mu2 * mu2;
        float rs2 = rsqrtf(var2 + 1e-5f);
        #pragma unroll
        for (int t = 0; t < 8; ++t) {
            int col = t * 16 + l15;
            int row = m0 + quad * 4 + rg;
            ffp[(size_t)row * 128 + col] =
                f2bf((attn[t][rg] - mu2) * rs2 * sgfp[col] + sbfp[col]);
        }
    }
}

// -------- FF mega: h1=gelu(ffp@W1+b1) -> h2=h1@W2+b2 -> out=xmid+LN(h2) ------
__global__ __launch_bounds__(128) void ff_mega_kernel(
    const u16* __restrict__ ffp, const u16* __restrict__ W1_t, const void* __restrict__ b1,
    const u16* __restrict__ W2_t, const void* __restrict__ b2,
    const float* __restrict__ xmid,
    const void* __restrict__ g_fo, const void* __restrict__ b_fo,
    const int* __restrict__ flags, void* __restrict__ outp)
{
    const int bf = flags[0];
    __shared__ __align__(16) u16 h1l[2][16][520];
    int tid = threadIdx.x;
    int wave = tid >> 6, lane = tid & 63;
    int quad = lane >> 4, l15 = lane & 15;
    int m0 = blockIdx.x * 32 + wave * 16;

    bf16x8 afr[4];
    const u16* ap = ffp + (size_t)(m0 + l15) * 128 + quad * 8;
    #pragma unroll
    for (int kc = 0; kc < 4; ++kc) afr[kc] = *(const bf16x8*)(ap + kc * 32);

    f32x4 acc1[32] = {};
    #pragma unroll
    for (int kc = 0; kc < 4; ++kc)
        #pragma unroll
        for (int t = 0; t < 32; ++t) {
            bf16x8 b = *(const bf16x8*)(W1_t + (size_t)(t*16 + l15) * 128 + kc*32 + quad*8);
            acc1[t] = __builtin_amdgcn_mfma_f32_16x16x32_bf16(afr[kc], b, acc1[t], 0, 0, 0);
        }
    #pragma unroll
    for (int t = 0; t < 32; ++t) {
        int col = t * 16 + l15;
        float bv = loadf(b1, col, bf);
        #pragma unroll
        for (int rg = 0; rg < 4; ++rg) {
            float v = acc1[t][rg] + bv;
            v = 0.5f * v * (1.0f + erff(v * 0.70710678118f));
            h1l[wave][quad * 4 + rg][col] = f2bf(v);
        }
    }
    __syncthreads();
    f32x4 acc2[8] = {};
    #pragma unroll
    for (int kc = 0; kc < 16; ++kc) {
        bf16x8 a = *(const bf16x8*)&h1l[wave][l15][kc * 32 + quad * 8];
        #pragma unroll
        for (int t = 0; t < 8; ++t) {
            bf16x8 b = *(const bf16x8*)(W2_t + (size_t)(t*16 + l15) * 512 + kc*32 + quad*8);
            acc2[t] = __builtin_amdgcn_mfma_f32_16x16x32_bf16(a, b, acc2[t], 0, 0, 0);
        }
    }
    float h2v[8][4];
    float sv[4] = {0,0,0,0}, sqv[4] = {0,0,0,0};
    #pragma unroll
    for (int t = 0; t < 8; ++t) {
        int col = t * 16 + l15;
        float bv = loadf(b2, col, bf);
        #pragma unroll
        for (int rg = 0; rg < 4; ++rg) {
            float v = acc2[t][rg] + bv;
            h2v[t][rg] = v; sv[rg] += v; sqv[rg] += v * v;
        }
    }
    #pragma unroll
    for (int rg = 0; rg < 4; ++rg)
        for (int m = 1; m < 16; m <<= 1) {
            sv[rg] += __shfl_xor(sv[rg], m, 64);
            sqv[rg] += __shfl_xor(sqv[rg], m, 64);
        }
    #pragma unroll
    for (int rg = 0; rg < 4; ++rg) {
        float mu = sv[rg] * (1.0f / 128.0f);
        float var = sqv[rg] * (1.0f / 128.0f) - mu * mu;
        float rs = rsqrtf(var + 1e-5f);
        int row = m0 + quad * 4 + rg;
        #pragma unroll
        for (int t = 0; t < 8; ++t) {
            int col = t * 16 + l15;
            float y = xmid[(size_t)row * 128 + col]
                    + (h2v[t][rg] - mu) * rs * loadf(g_fo, col, bf) + loadf(b_fo, col, bf);
            if (bf) ((u16*)outp)[(size_t)row * 128 + col] = f2bf(y);
            else    ((float*)outp)[(size_t)row * 128 + col] = y;
        }
    }
}

extern "C" void kernel_launch(void* const* d_in, const int* in_sizes, int n_in,
                              void* d_out, int out_size, void* d_ws, size_t ws_size,
                              hipStream_t stream)
{
    const int N = NN, E = NE;
    const void* x       = d_in[0];
    const void* r       = d_in[1];
    const int*  ei      = (const int*)d_in[2];
    const void* ln_x_g  = d_in[3];
    const void* ln_x_b  = d_in[4];
    const void* ln_r_g  = d_in[5];
    const void* ln_r_b  = d_in[6];
    const void* ln_po_g = d_in[7];
    const void* ln_po_b = d_in[8];
    const void* ln_fp_g = d_in[9];
    const void* ln_fp_b = d_in[10];
    const void* ln_fo_g = d_in[11];
    const void* ln_fo_b = d_in[12];
    const void* Wq      = d_in[13];
    const void* Wk      = d_in[14];
    const void* Wv      = d_in[15];
    const void* Wkr     = d_in[16];
    const void* Wvr     = d_in[17];
    const void* Wo      = d_in[18];
    const void* Wg      = d_in[19];
    const void* bg      = d_in[20];
    const void* Ws      = d_in[21];
    const void* bs      = d_in[22];
    const void* W1      = d_in[23];
    const void* b1      = d_in[24];
    const void* W2      = d_in[25];
    const void* b2      = d_in[26];

    // ---- workspace ~89 MB ----
    float* ws = (float*)d_ws;
    size_t off = 0;
    auto alloc = [&](size_t n) { float* p = ws + off; off += n; return p; };
    const size_t U = (size_t)N * 64;
    u16*   xs_bf  = (u16*)alloc(U);
    u16*   qkv_bf = (u16*)alloc(3 * U);        // [N,384]: phi(q)|k|v
    u16*   att_bf = (u16*)alloc(U);
    float* sbuf   = alloc((size_t)N * 128);
    float* gxs    = alloc((size_t)N * 128);
    float* xmid   = alloc((size_t)N * 128);
    u16*   ffp_bf = (u16*)alloc(U);
    u16*   ve_s   = (u16*)alloc((size_t)E * 64);   // [E,128] bf16
    float* p_arr  = alloc((size_t)E * 8);          // [E,8] fp32
    int*   e32    = (int*)alloc((size_t)2 * E);
    int*   perm   = (int*)alloc(E);
    int*   ssrc   = (int*)alloc(E);
    int*   sdst   = (int*)alloc(E);
    int*   hist   = (int*)alloc(NN);
    int*   offs   = (int*)alloc(NN + 1);
    int*   cursor = (int*)alloc(NN + 1);
    int*   flags  = (int*)alloc(16);
    u16*   wt     = (u16*)alloc(139264);

    u16* Wq_t  = wt;                 // [384][128] qkv block
    u16* Wkr_t = wt + 49152;
    u16* Wvr_t = wt + 65536;
    u16* Wo_t  = wt + 81920;
    u16* Ws_t  = wt + 98304;
    u16* Wg_t  = wt + 114688;        // [128][256]
    u16* W1_t  = wt + 147456;        // [512][128]
    u16* W2_t  = wt + 212992;        // [128][512]

    // 0. detection + conversion + dst-sort
    dtype_detect_kernel<<<1, 256, 0, stream>>>((const u16*)x, flags);
    edetect_kernel<<<NE / 1024, 256, 0, stream>>>(ei, flags);
    cvt_edges_kernel<<<(2 * E + 255) / 256, 256, 0, stream>>>(ei, flags, e32, hist);
    hist_kernel<<<(E + 255) / 256, 256, 0, stream>>>(e32, hist);
    scan_kernel<<<1, 256, 0, stream>>>(hist, offs, cursor);
    scatter_kernel<<<(E + 255) / 256, 256, 0, stream>>>(e32, cursor, perm, ssrc, sdst);

    WTArgs wa;
    int t0 = 0;
    auto setw = [&](int i, const void* w, u16* wtp, int K, int Ncol) {
        wa.d[i] = WDesc{w, wtp, K, Ncol, t0};
        t0 += (K / 32) * (Ncol / 32);
    };
    setw(0, Wq, Wq_t, 128, 128);
    setw(1, Wk, wt + 16384, 128, 128);
    setw(2, Wv, wt + 32768, 128, 128);
    setw(3, Wkr, Wkr_t, 128, 128);
    setw(4, Wvr, Wvr_t, 128, 128);
    setw(5, Wo, Wo_t, 128, 128);
    setw(6, Ws, Ws_t, 128, 128);
    setw(7, Wg, Wg_t, 256, 128);
    setw(8, W1, W1_t, 128, 512);
    setw(9, W2, W2_t, 512, 128);
    wtrans_kernel<<<t0, 256, 0, stream>>>(wa, flags);

    // 1. LN(x) -> bf16
    ln_in_kernel<<<N / 4, 256, 0, stream>>>(x, ln_x_g, ln_x_b, flags, xs_bf, N);

    // 2. fused qkv GEMM (phi on q-block)
    mfma_gemm_kernel<<<dim3(6, N / 64), 256, 0, stream>>>(
        xs_bf, Wq_t, 128, nullptr, flags, qkv_bf, N, 128, 384, 3, 1);

    // 3. independent node GEMMs
    mfma_gemm_kernel<<<dim3(2, N / 64), 256, 0, stream>>>(
        xs_bf, Ws_t, 128, bs, flags, sbuf, N, 128, 128, 0, 0);
    mfma_gemm_kernel<<<dim3(2, N / 64), 256, 0, stream>>>(
        xs_bf, Wg_t + 128, 256, bg, flags, gxs, N, 128, 128, 0, 0);

    // 4. edge projection (sorted, atomic-free)
    edge_proj_kernel<<<E / 32, 256, 0, stream>>>(r, ln_r_g, ln_r_b, Wkr_t, Wvr_t,
                                                 perm, ssrc, sdst, qkv_bf, flags,
                                                 p_arr, ve_s);

    // 5. node accumulate + normalize -> att bf16
    node_acc_kernel<<<N / 4, 256, 0, stream>>>(p_arr, ve_s, offs, att_bf);

    // 6. gate mega -> xmid, ffp
    gate_mega_kernel<<<N / 64, 256, 0, stream>>>(att_bf, Wo_t, Wg_t, gxs, sbuf,
                                                 x, ln_po_g, ln_po_b, ln_fp_g, ln_fp_b,
                                                 flags, xmid, ffp_bf);

    // 7. ff mega -> d_out
    ff_mega_kernel<<<N / 32, 128, 0, stream>>>(ffp_bf, W1_t, b1, W2_t, b2,
                                               xmid, ln_fo_g, ln_fo_b, flags, d_out);
}